// Round 3
// baseline (335.628 us; speedup 1.0000x reference)
//
#include <hip/hip_runtime.h>
#include <hip/hip_bf16.h>
#include <cstddef>
#include <cstdint>

// Problem constants
#define NN 10000
#define EE 160000
#define ETOT (EE + NN)
#define F_IN 128
#define H1 10
#define C1 128
#define HC1 1280
#define H2 1
#define C2 1024
#define HC2 1024
#define OUT_DIM 1024

typedef __attribute__((ext_vector_type(4))) float f32x4;
typedef __attribute__((ext_vector_type(8))) short s16x8;
typedef unsigned int u32;
typedef unsigned short u16;

__device__ __forceinline__ float bf2f(u16 v) {
    union { u32 u; float f; } x; x.u = ((u32)v) << 16; return x.f;
}
__device__ __forceinline__ u16 f2bf(float f) {
    union { float f; u32 u; } x; x.f = f;
    u32 u = x.u;
    u32 r = (u + 0x7fffu + ((u >> 16) & 1u)) >> 16;   // RNE
    return (u16)r;
}

__device__ __forceinline__ void gld16(const void* g, void* l) {
    __builtin_amdgcn_global_load_lds((const __attribute__((address_space(1))) u32*)g,
                                     (__attribute__((address_space(3))) u32*)l, 16, 0, 0);
}

// ---------------- conversions ----------------
__global__ void f32_to_bf16_kernel(const float* __restrict__ in, u16* __restrict__ out, int n) {
    int i = blockIdx.x * 256 + threadIdx.x;
    if (i < n) out[i] = f2bf(in[i]);
}

// in: [K][N] row-major f32; out: [N][K] bf16
__global__ void transpose_bf16_kernel(const float* __restrict__ in, u16* __restrict__ out,
                                      int K, int N) {
    int n = blockIdx.x * 16 + threadIdx.x;
    int k = blockIdx.y * 16 + threadIdx.y;
    if (n < N && k < K) out[(size_t)n * K + k] = f2bf(in[(size_t)k * N + n]);
}

// ---------------- CSR build ----------------
__global__ void hist_kernel(const int* __restrict__ edst, int* __restrict__ deg) {
    int e = blockIdx.x * 256 + threadIdx.x;
    if (e >= ETOT) return;
    int d = (e < EE) ? edst[e] : (e - EE);
    atomicAdd(&deg[d], 1);
}

__global__ void scan_kernel(const int* __restrict__ deg, int* __restrict__ row_start) {
    __shared__ int buf[1024];
    int carry = 0;
    for (int base = 0; base < NN; base += 1024) {
        int i = base + threadIdx.x;
        int v = (i < NN) ? deg[i] : 0;
        buf[threadIdx.x] = v;
        __syncthreads();
        for (int off = 1; off < 1024; off <<= 1) {
            int t = (threadIdx.x >= off) ? buf[threadIdx.x - off] : 0;
            __syncthreads();
            buf[threadIdx.x] += t;
            __syncthreads();
        }
        int incl = buf[threadIdx.x];
        if (i < NN) row_start[i] = carry + incl - v;   // exclusive
        carry += buf[1023];
        __syncthreads();
    }
    if (threadIdx.x == 0) row_start[NN] = carry;
}

__global__ void fill_kernel(const int* __restrict__ esrc, const int* __restrict__ edst,
                            const int* __restrict__ row_start, int* __restrict__ cursor,
                            int* __restrict__ slot_src) {
    int e = blockIdx.x * 256 + threadIdx.x;
    if (e >= ETOT) return;
    int s, d;
    if (e < EE) { s = esrc[e]; d = edst[e]; }
    else        { s = d = e - EE; }
    int pos = atomicAdd(&cursor[d], 1);
    slot_src[row_start[d] + pos] = s;
}

// ---------------- bf16 MFMA GEMM: C = A[MxK] * Bt[NxK]^T ----------------
// 128x128 tile, 4 waves (2x2), 16x16x32 MFMA, BK=32, global_load_lds staging.
// BIAS_RELU==0: store bf16 (no bias/act). BIAS_RELU==1: +bias, relu, store f32.
template<int BIAS_RELU>
__global__ __launch_bounds__(256, 2)
void gemm_bf16(const u16* __restrict__ A, const u16* __restrict__ Bt,
               const float* __restrict__ bias, void* __restrict__ Cout,
               int M, int N, int K) {
    __shared__ u16 Als[128 * 32];
    __shared__ u16 Bls[128 * 32];
    const int tid  = threadIdx.x;
    const int wave = tid >> 6;
    const int lane = tid & 63;
    const int bm = blockIdx.y * 128;
    const int bn = blockIdx.x * 128;
    const int wr = wave >> 1, wc = wave & 1;   // 2x2 waves, each 64x64
    const int lr = lane & 15;                  // fragment row/col within 16
    const int kc = lane >> 4;                  // k-chunk 0..3

    f32x4 acc[4][4] = {};

    // staging geometry: per 4096B chunk, thread t covers byte t*16
    const int srow = tid >> 2;             // 0..63
    const int scol = (tid & 3) * 8;        // element col in [0,32)
    int arow0 = bm + srow;       if (arow0 >= M) arow0 = M - 1;   // clamp: pad rows never stored
    int arow1 = bm + 64 + srow;  if (arow1 >= M) arow1 = M - 1;
    const int brow0 = bn + srow;           // N is a multiple of 128
    const int brow1 = bn + 64 + srow;

    for (int k0 = 0; k0 < K; k0 += 32) {
        gld16(A  + (size_t)arow0 * K + k0 + scol, &Als[(size_t)wave * 512]);
        gld16(A  + (size_t)arow1 * K + k0 + scol, &Als[2048 + (size_t)wave * 512]);
        gld16(Bt + (size_t)brow0 * K + k0 + scol, &Bls[(size_t)wave * 512]);
        gld16(Bt + (size_t)brow1 * K + k0 + scol, &Bls[2048 + (size_t)wave * 512]);
        __syncthreads();

        s16x8 af[4], bg[4];
#pragma unroll
        for (int i = 0; i < 4; ++i)
            af[i] = *(const s16x8*)&Als[(wr * 64 + i * 16 + lr) * 32 + kc * 8];
#pragma unroll
        for (int j = 0; j < 4; ++j)
            bg[j] = *(const s16x8*)&Bls[(wc * 64 + j * 16 + lr) * 32 + kc * 8];
#pragma unroll
        for (int i = 0; i < 4; ++i)
#pragma unroll
            for (int j = 0; j < 4; ++j)
                acc[i][j] = __builtin_amdgcn_mfma_f32_16x16x32_bf16(af[i], bg[j], acc[i][j], 0, 0, 0);
        __syncthreads();
    }

    // C/D layout: col = lane&15, row = (lane>>4)*4 + reg
#pragma unroll
    for (int i = 0; i < 4; ++i) {
#pragma unroll
        for (int r = 0; r < 4; ++r) {
            int m = bm + wr * 64 + i * 16 + kc * 4 + r;
            if (m >= M) continue;
#pragma unroll
            for (int j = 0; j < 4; ++j) {
                int n = bn + wc * 64 + j * 16 + lr;
                float v = acc[i][j][r];
                if (BIAS_RELU) {
                    v += bias[n];
                    v = fmaxf(v, 0.f);
                    ((float*)Cout)[(size_t)m * N + n] = v;
                } else {
                    ((u16*)Cout)[(size_t)m * N + n] = f2bf(v);
                }
            }
        }
    }
}

// ---------------- attention logits from bf16 h ----------------
__global__ void att_logits_bf16(const u16* __restrict__ h, const float* __restrict__ att_s,
                                const float* __restrict__ att_d, float* __restrict__ a_s,
                                float* __restrict__ a_d, int H, int C) {
    int nh = blockIdx.x;
    int n = nh / H, hd = nh % H;
    int lane = threadIdx.x;
    const u16* row = h + (size_t)n * H * C + (size_t)hd * C;
    float ps = 0.f, pd = 0.f;
    for (int c = lane; c < C; c += 64) {
        float v = bf2f(row[c]);
        ps += v * att_s[hd * C + c];
        pd += v * att_d[hd * C + c];
    }
    for (int off = 32; off; off >>= 1) {
        ps += __shfl_down(ps, off);
        pd += __shfl_down(pd, off);
    }
    if (lane == 0) {
        a_s[n * H + hd] = ps;
        a_d[n * H + hd] = pd;
    }
}

// ---------------- per-dst softmax over in-edges (CSR) ----------------
__global__ void att_alpha(const int* __restrict__ row_start, const int* __restrict__ slot_src,
                          const float* __restrict__ a_s, const float* __restrict__ a_d,
                          float* __restrict__ alpha, int H) {
    int d = blockIdx.x;
    int lane = threadIdx.x;
    int s0 = row_start[d], s1 = row_start[d + 1];
    for (int hd = 0; hd < H; ++hd) {
        float ad = a_d[d * H + hd];
        float sum = 0.f;
        for (int s = s0 + lane; s < s1; s += 64) {
            float e = a_s[slot_src[s] * H + hd] + ad;
            e = (e > 0.f) ? e : 0.2f * e;          // leaky_relu 0.2
            float ex = expf(e);                     // logits are small by construction
            alpha[(size_t)s * H + hd] = ex;
            sum += ex;
        }
        for (int off = 32; off; off >>= 1) sum += __shfl_down(sum, off);
        sum = __shfl(sum, 0);
        float inv = 1.f / (sum + 1e-16f);
        for (int s = s0 + lane; s < s1; s += 64) alpha[(size_t)s * H + hd] *= inv;
    }
}

// ---------------- scatter v2: one block per dst, full channel row, LDS-staged edges ----
// out[d,c] = act( sum_e alpha[e,h(c)] * h[src_e, c] + bias[c] ), bf16 in/out.
// ACT: 1 = elu, 2 = relu. VEC channels per thread (4 -> 8B loads, 8 -> 16B loads).
template<int VEC>
__device__ __forceinline__ void fma_bf16vec(float* acc, const u16* p, float a) {
    if constexpr (VEC == 4) {
        uint2 q = *(const uint2*)p;
        acc[0] += a * bf2f((u16)(q.x & 0xffff));
        acc[1] += a * bf2f((u16)(q.x >> 16));
        acc[2] += a * bf2f((u16)(q.y & 0xffff));
        acc[3] += a * bf2f((u16)(q.y >> 16));
    } else {
        uint4 q = *(const uint4*)p;
        acc[0] += a * bf2f((u16)(q.x & 0xffff));
        acc[1] += a * bf2f((u16)(q.x >> 16));
        acc[2] += a * bf2f((u16)(q.y & 0xffff));
        acc[3] += a * bf2f((u16)(q.y >> 16));
        acc[4] += a * bf2f((u16)(q.z & 0xffff));
        acc[5] += a * bf2f((u16)(q.z >> 16));
        acc[6] += a * bf2f((u16)(q.w & 0xffff));
        acc[7] += a * bf2f((u16)(q.w >> 16));
    }
}

template<int ACT, int H, int C, int VEC>
__global__ __launch_bounds__(H * C / VEC)
void gat_scatter2(const int* __restrict__ row_start, const int* __restrict__ slot_src,
                  const float* __restrict__ alpha, const u16* __restrict__ h,
                  const float* __restrict__ bias, u16* __restrict__ out) {
    constexpr int HC = H * C;
    constexpr int NT = HC / VEC;
    constexpr int CHUNK = 64;
    __shared__ int   ls_src[CHUNK];
    __shared__ float ls_alpha[CHUNK * H];
    const int d = blockIdx.x;
    const int tid = threadIdx.x;
    const int c0 = tid * VEC;
    const int hd = c0 / C;
    const int s0 = row_start[d], s1 = row_start[d + 1];
    float acc[VEC] = {};
    for (int base = s0; base < s1; base += CHUNK) {
        int cnt = min(CHUNK, s1 - base);
        if (tid < cnt) ls_src[tid] = slot_src[base + tid];
        for (int i = tid; i < cnt * H; i += NT) ls_alpha[i] = alpha[(size_t)base * H + i];
        __syncthreads();
        int j = 0;
        for (; j + 2 <= cnt; j += 2) {
            int   srcA = ls_src[j],            srcB = ls_src[j + 1];
            float aA   = ls_alpha[j * H + hd], aB   = ls_alpha[(j + 1) * H + hd];
            fma_bf16vec<VEC>(acc, h + (size_t)srcA * HC + c0, aA);
            fma_bf16vec<VEC>(acc, h + (size_t)srcB * HC + c0, aB);
        }
        if (j < cnt)
            fma_bf16vec<VEC>(acc, h + (size_t)ls_src[j] * HC + c0, ls_alpha[j * H + hd]);
        __syncthreads();
    }
#pragma unroll
    for (int k = 0; k < VEC; ++k) {
        float v = acc[k] + bias[c0 + k];
        if (ACT == 1) v = (v > 0.f) ? v : (expf(v) - 1.f);  // elu
        else          v = fmaxf(v, 0.f);                     // relu
        acc[k] = v;
    }
    u16 os[VEC];
#pragma unroll
    for (int k = 0; k < VEC; ++k) os[k] = f2bf(acc[k]);
    if constexpr (VEC == 4) {
        uint2 q;
        q.x = (u32)os[0] | ((u32)os[1] << 16);
        q.y = (u32)os[2] | ((u32)os[3] << 16);
        *(uint2*)(out + (size_t)d * HC + c0) = q;
    } else {
        uint4 q;
        q.x = (u32)os[0] | ((u32)os[1] << 16);
        q.y = (u32)os[2] | ((u32)os[3] << 16);
        q.z = (u32)os[4] | ((u32)os[5] << 16);
        q.w = (u32)os[6] | ((u32)os[7] << 16);
        *(uint4*)(out + (size_t)d * HC + c0) = q;
    }
}

extern "C" void kernel_launch(void* const* d_in, const int* in_sizes, int n_in,
                              void* d_out, int out_size, void* d_ws, size_t ws_size,
                              hipStream_t stream) {
    const float* node      = (const float*)d_in[0];
    const int*   esrc      = (const int*)d_in[1];          // edge_index[0]
    const int*   edst      = ((const int*)d_in[1]) + EE;   // edge_index[1]
    const float* W1        = (const float*)d_in[2];
    const float* att_src1  = (const float*)d_in[3];
    const float* att_dst1  = (const float*)d_in[4];
    const float* b1        = (const float*)d_in[5];
    const float* W2        = (const float*)d_in[6];
    const float* att_src2  = (const float*)d_in[7];
    const float* att_dst2  = (const float*)d_in[8];
    const float* b2        = (const float*)d_in[9];
    const float* fc_w      = (const float*)d_in[10];
    const float* fc_b      = (const float*)d_in[11];
    float* out = (float*)d_out;

    // ---- workspace layout (bf16 first, then f32, then ints) ----
    u16* bufA  = (u16*)d_ws;                        // [NN*HC1]  h1b, later h2b
    u16* bufB  = bufA + (size_t)NN * HC1;           // [NN*HC1]  x2b, later out2b
    u16* nodeb = bufB + (size_t)NN * HC1;           // [NN*F_IN]
    u16* w1t   = nodeb + (size_t)NN * F_IN;         // [HC1*F_IN]
    u16* w2t   = w1t + (size_t)HC1 * F_IN;          // [HC2*HC1]
    u16* fcwt  = w2t + (size_t)HC2 * HC1;           // [OUT_DIM*OUT_DIM]
    float* alpha = (float*)(fcwt + (size_t)OUT_DIM * OUT_DIM);  // [ETOT*H1]
    float* a_s1  = alpha + (size_t)ETOT * H1;       // [NN*H1]
    float* a_d1  = a_s1 + (size_t)NN * H1;
    float* a_s2  = a_d1 + (size_t)NN * H1;          // [NN]
    float* a_d2  = a_s2 + NN;
    int* deg       = (int*)(a_d2 + NN);
    int* cursor    = deg + NN;
    int* row_start = cursor + NN;                   // [NN+1]
    int* slot_src  = row_start + NN + 8;            // [ETOT]

    // ---- conversions ----
    f32_to_bf16_kernel<<<(NN * F_IN + 255) / 256, 256, 0, stream>>>(node, nodeb, NN * F_IN);
    transpose_bf16_kernel<<<dim3(HC1 / 16, F_IN / 16), dim3(16, 16), 0, stream>>>(W1, w1t, F_IN, HC1);
    transpose_bf16_kernel<<<dim3(HC2 / 16, HC1 / 16), dim3(16, 16), 0, stream>>>(W2, w2t, HC1, HC2);
    transpose_bf16_kernel<<<dim3(OUT_DIM / 16, OUT_DIM / 16), dim3(16, 16), 0, stream>>>(fc_w, fcwt, OUT_DIM, OUT_DIM);

    // ---- CSR build ----
    hipMemsetAsync(deg, 0, 2 * NN * sizeof(int), stream);  // deg + cursor
    hist_kernel<<<(ETOT + 255) / 256, 256, 0, stream>>>(edst, deg);
    scan_kernel<<<1, 1024, 0, stream>>>(deg, row_start);
    fill_kernel<<<(ETOT + 255) / 256, 256, 0, stream>>>(esrc, edst, row_start, cursor, slot_src);

    // ---- layer 1 ----
    gemm_bf16<0><<<dim3(HC1 / 128, (NN + 127) / 128), 256, 0, stream>>>(nodeb, w1t, nullptr, bufA, NN, HC1, F_IN);
    att_logits_bf16<<<NN * H1, 64, 0, stream>>>(bufA, att_src1, att_dst1, a_s1, a_d1, H1, C1);
    att_alpha<<<NN, 64, 0, stream>>>(row_start, slot_src, a_s1, a_d1, alpha, H1);
    gat_scatter2<1, H1, C1, 4><<<NN, HC1 / 4, 0, stream>>>(row_start, slot_src, alpha, bufA, b1, bufB);

    // ---- layer 2 ----
    gemm_bf16<0><<<dim3(HC2 / 128, (NN + 127) / 128), 256, 0, stream>>>(bufB, w2t, nullptr, bufA, NN, HC2, HC1);
    att_logits_bf16<<<NN * H2, 64, 0, stream>>>(bufA, att_src2, att_dst2, a_s2, a_d2, H2, C2);
    att_alpha<<<NN, 64, 0, stream>>>(row_start, slot_src, a_s2, a_d2, alpha, H2);
    gat_scatter2<2, H2, C2, 8><<<NN, HC2 / 8, 0, stream>>>(row_start, slot_src, alpha, bufA, b2, bufB);

    // ---- fc: out = relu(out2 @ fc_w + fc_b), f32 out ----
    gemm_bf16<1><<<dim3(OUT_DIM / 128, (NN + 127) / 128), 256, 0, stream>>>(bufB, fcwt, fc_b, out, NN, OUT_DIM, OUT_DIM);
}

// Round 4
// 271.322 us; speedup vs baseline: 1.2370x; 1.2370x over previous
//
#include <hip/hip_runtime.h>
#include <hip/hip_bf16.h>
#include <cstddef>
#include <cstdint>

// Problem constants
#define NN 10000
#define EE 160000
#define ETOT (EE + NN)
#define F_IN 128
#define H1 10
#define C1 128
#define HC1 1280
#define H2 1
#define C2 1024
#define HC2 1024
#define OUT_DIM 1024

typedef __attribute__((ext_vector_type(4))) float f32x4;
typedef __attribute__((ext_vector_type(8))) short s16x8;
typedef unsigned int u32;
typedef unsigned short u16;

__device__ __forceinline__ float bf2f(u16 v) {
    union { u32 u; float f; } x; x.u = ((u32)v) << 16; return x.f;
}
__device__ __forceinline__ u16 f2bf(float f) {
    union { float f; u32 u; } x; x.f = f;
    u32 u = x.u;
    u32 r = (u + 0x7fffu + ((u >> 16) & 1u)) >> 16;   // RNE
    return (u16)r;
}

__device__ __forceinline__ void gld16(const void* g, void* l) {
    __builtin_amdgcn_global_load_lds((const __attribute__((address_space(1))) u32*)g,
                                     (__attribute__((address_space(3))) u32*)l, 16, 0, 0);
}

// ---------------- conversions ----------------
__global__ void f32_to_bf16_kernel(const float* __restrict__ in, u16* __restrict__ out, int n) {
    int i = blockIdx.x * 256 + threadIdx.x;
    if (i < n) out[i] = f2bf(in[i]);
}

// in: [K][N] row-major f32; out: [N][K] bf16. K,N multiples of 16. Coalesced both sides.
__global__ void transpose_bf16_kernel(const float* __restrict__ in, u16* __restrict__ out,
                                      int K, int N) {
    __shared__ u16 t[16][17];
    int n0 = blockIdx.x * 16, k0 = blockIdx.y * 16;
    t[threadIdx.y][threadIdx.x] = f2bf(in[(size_t)(k0 + threadIdx.y) * N + n0 + threadIdx.x]);
    __syncthreads();
    out[(size_t)(n0 + threadIdx.y) * K + k0 + threadIdx.x] = t[threadIdx.x][threadIdx.y];
}

// ---------------- CSR build ----------------
__global__ void hist_kernel(const int* __restrict__ edst, int* __restrict__ deg) {
    int e = blockIdx.x * 256 + threadIdx.x;
    if (e >= ETOT) return;
    int d = (e < EE) ? edst[e] : (e - EE);
    atomicAdd(&deg[d], 1);
}

// shfl-based single-block scan (1024 threads)
__global__ void scan_kernel(const int* __restrict__ deg, int* __restrict__ row_start) {
    __shared__ int wsum[16];
    const int tid = threadIdx.x;
    const int lane = tid & 63;
    const int wid = tid >> 6;
    int carry = 0;
    for (int base = 0; base < NN; base += 1024) {
        int i = base + tid;
        int v = (i < NN) ? deg[i] : 0;
        int x = v;
#pragma unroll
        for (int o = 1; o < 64; o <<= 1) {
            int t = __shfl_up(x, o);
            if (lane >= o) x += t;
        }
        if (lane == 63) wsum[wid] = x;
        __syncthreads();
        if (wid == 0) {
            int w = (lane < 16) ? wsum[lane] : 0;
#pragma unroll
            for (int o = 1; o < 16; o <<= 1) {
                int t = __shfl_up(w, o);
                if (lane >= o) w += t;
            }
            if (lane < 16) wsum[lane] = w;
        }
        __syncthreads();
        int woff = (wid == 0) ? 0 : wsum[wid - 1];
        if (i < NN) row_start[i] = carry + woff + x - v;   // exclusive
        carry += wsum[15];
        __syncthreads();
    }
    if (tid == 0) row_start[NN] = carry;
}

__global__ void fill_kernel(const int* __restrict__ esrc, const int* __restrict__ edst,
                            const int* __restrict__ row_start, int* __restrict__ cursor,
                            int* __restrict__ slot_src) {
    int e = blockIdx.x * 256 + threadIdx.x;
    if (e >= ETOT) return;
    int s, d;
    if (e < EE) { s = esrc[e]; d = edst[e]; }
    else        { s = d = e - EE; }
    int pos = atomicAdd(&cursor[d], 1);
    slot_src[row_start[d] + pos] = s;
}

// ---------------- bf16 MFMA GEMM: C = A[MxK] * Bt[NxK]^T ----------------
template<int BIAS_RELU>
__global__ __launch_bounds__(256, 2)
void gemm_bf16(const u16* __restrict__ A, const u16* __restrict__ Bt,
               const float* __restrict__ bias, void* __restrict__ Cout,
               int M, int N, int K) {
    __shared__ u16 Als[128 * 32];
    __shared__ u16 Bls[128 * 32];
    const int tid  = threadIdx.x;
    const int wave = tid >> 6;
    const int lane = tid & 63;
    const int bm = blockIdx.y * 128;
    const int bn = blockIdx.x * 128;
    const int wr = wave >> 1, wc = wave & 1;   // 2x2 waves, each 64x64
    const int lr = lane & 15;
    const int kc = lane >> 4;

    f32x4 acc[4][4] = {};

    const int srow = tid >> 2;
    const int scol = (tid & 3) * 8;
    int arow0 = bm + srow;       if (arow0 >= M) arow0 = M - 1;
    int arow1 = bm + 64 + srow;  if (arow1 >= M) arow1 = M - 1;
    const int brow0 = bn + srow;
    const int brow1 = bn + 64 + srow;

    for (int k0 = 0; k0 < K; k0 += 32) {
        gld16(A  + (size_t)arow0 * K + k0 + scol, &Als[(size_t)wave * 512]);
        gld16(A  + (size_t)arow1 * K + k0 + scol, &Als[2048 + (size_t)wave * 512]);
        gld16(Bt + (size_t)brow0 * K + k0 + scol, &Bls[(size_t)wave * 512]);
        gld16(Bt + (size_t)brow1 * K + k0 + scol, &Bls[2048 + (size_t)wave * 512]);
        __syncthreads();

        s16x8 af[4], bg[4];
#pragma unroll
        for (int i = 0; i < 4; ++i)
            af[i] = *(const s16x8*)&Als[(wr * 64 + i * 16 + lr) * 32 + kc * 8];
#pragma unroll
        for (int j = 0; j < 4; ++j)
            bg[j] = *(const s16x8*)&Bls[(wc * 64 + j * 16 + lr) * 32 + kc * 8];
#pragma unroll
        for (int i = 0; i < 4; ++i)
#pragma unroll
            for (int j = 0; j < 4; ++j)
                acc[i][j] = __builtin_amdgcn_mfma_f32_16x16x32_bf16(af[i], bg[j], acc[i][j], 0, 0, 0);
        __syncthreads();
    }

#pragma unroll
    for (int i = 0; i < 4; ++i) {
#pragma unroll
        for (int r = 0; r < 4; ++r) {
            int m = bm + wr * 64 + i * 16 + kc * 4 + r;
            if (m >= M) continue;
#pragma unroll
            for (int j = 0; j < 4; ++j) {
                int n = bn + wc * 64 + j * 16 + lr;
                float v = acc[i][j][r];
                if (BIAS_RELU) {
                    v += bias[n];
                    v = fmaxf(v, 0.f);
                    ((float*)Cout)[(size_t)m * N + n] = v;
                } else {
                    ((u16*)Cout)[(size_t)m * N + n] = f2bf(v);
                }
            }
        }
    }
}

// ---------------- logits v2: one block = 2 nodes, head loop inside ----------------
template<int H, int C>
__global__ __launch_bounds__(128)
void att_logits2(const u16* __restrict__ h, const float* __restrict__ att_s,
                 const float* __restrict__ att_d, float* __restrict__ a_s,
                 float* __restrict__ a_d) {
    const int n = blockIdx.x * 2 + (threadIdx.x >> 6);
    const int lane = threadIdx.x & 63;
    const u16* row = h + (size_t)n * H * C;
#pragma unroll
    for (int hd = 0; hd < H; ++hd) {
        float ps = 0.f, pd = 0.f;
        for (int c = lane * 2; c < C; c += 128) {
            u32 q = *(const u32*)(row + hd * C + c);
            float v0 = bf2f((u16)(q & 0xffff));
            float v1 = bf2f((u16)(q >> 16));
            float2 s = *(const float2*)(att_s + hd * C + c);
            float2 dd = *(const float2*)(att_d + hd * C + c);
            ps += v0 * s.x + v1 * s.y;
            pd += v0 * dd.x + v1 * dd.y;
        }
#pragma unroll
        for (int off = 32; off; off >>= 1) {
            ps += __shfl_down(ps, off);
            pd += __shfl_down(pd, off);
        }
        if (lane == 0) {
            a_s[n * H + hd] = ps;
            a_d[n * H + hd] = pd;
        }
    }
}

// ---------------- alpha v2: unnormalized exp + per-(d,h) inverse sum ----------------
// One wave per dst (2 dst per block). Edge-per-lane, contiguous a_s row loads.
template<int H>
__global__ __launch_bounds__(128)
void att_alpha2(const int* __restrict__ row_start, const int* __restrict__ slot_src,
                const float* __restrict__ a_s, const float* __restrict__ a_d,
                float* __restrict__ exal, float* __restrict__ inv) {
    const int d = blockIdx.x * 2 + (threadIdx.x >> 6);
    const int lane = threadIdx.x & 63;
    const int s0 = row_start[d], s1 = row_start[d + 1];
    float ad[H];
#pragma unroll
    for (int hd = 0; hd < H; ++hd) ad[hd] = a_d[(size_t)d * H + hd];
    float sums[H];
#pragma unroll
    for (int hd = 0; hd < H; ++hd) sums[hd] = 0.f;

    for (int base = s0; base < s1; base += 64) {
        int e = base + lane;
        bool ok = (e < s1);
        int src = ok ? slot_src[e] : 0;
        float as[H];
        if constexpr (H == 1) {
            as[0] = ok ? a_s[src] : 0.f;
        } else {
            const float2* asp = (const float2*)(a_s + (size_t)src * H);
#pragma unroll
            for (int i = 0; i < H / 2; ++i) {
                float2 q = ok ? asp[i] : make_float2(0.f, 0.f);
                as[2 * i] = q.x; as[2 * i + 1] = q.y;
            }
        }
        float ex[H];
#pragma unroll
        for (int hd = 0; hd < H; ++hd) {
            float t = as[hd] + ad[hd];
            t = (t > 0.f) ? t : 0.2f * t;          // leaky_relu 0.2
            float x = ok ? expf(t) : 0.f;          // logits small by construction
            ex[hd] = x;
            sums[hd] += x;
        }
        if (ok) {
            if constexpr (H == 1) {
                exal[e] = ex[0];
            } else {
                float2* op = (float2*)(exal + (size_t)e * H);
#pragma unroll
                for (int i = 0; i < H / 2; ++i) op[i] = make_float2(ex[2 * i], ex[2 * i + 1]);
            }
        }
    }
#pragma unroll
    for (int hd = 0; hd < H; ++hd) {
#pragma unroll
        for (int off = 32; off; off >>= 1) sums[hd] += __shfl_down(sums[hd], off);
    }
    if (lane == 0) {
#pragma unroll
        for (int hd = 0; hd < H; ++hd) inv[(size_t)d * H + hd] = 1.f / (sums[hd] + 1e-16f);
    }
}

// ---------------- scatter v4: segment-major, shfl-broadcast metadata, 4-deep ILP ----
// out[d,c] = act( inv[d,h]*sum_e ex[e,h]*h[src_e,c] + bias[c] ), bf16 in/out.
// One wave handles one (dst, 256-ch segment); 2 dst-waves per block. No LDS/barriers.
template<int ACT, int H, int C, int SEG>
__global__ __launch_bounds__(128)
void gat_scatter4(const int* __restrict__ row_start, const int* __restrict__ slot_src,
                  const float* __restrict__ exal, const float* __restrict__ inv,
                  const u16* __restrict__ h, const float* __restrict__ bias,
                  u16* __restrict__ out) {
    constexpr int HC = H * C;
    constexpr bool TWO = (SEG == 2 * C);   // segment spans 2 heads (layer 1)
    const int d = blockIdx.x * 2 + (threadIdx.x >> 6);
    const int lane = threadIdx.x & 63;
    const int c0 = blockIdx.y * SEG + lane * 4;
    const int hd = c0 / C;
    const int hA = (blockIdx.y * SEG) / C;
    const int s0 = row_start[d], s1 = row_start[d + 1];

    float acc0[4] = {}, acc1[4] = {}, acc2[4] = {}, acc3[4] = {};

    for (int base = s0; base < s1; base += 64) {
        int e = base + lane;
        bool ok = (e < s1);
        int mySrc = 0; float myA0 = 0.f, myA1 = 0.f;
        if (ok) {
            mySrc = slot_src[e];
            myA0 = exal[(size_t)e * H + hA];
            if (TWO) myA1 = exal[(size_t)e * H + hA + 1];
        }
        int cnt = min(64, s1 - base);
        int j = 0;
        for (; j + 4 <= cnt; j += 4) {
            int sA = __shfl(mySrc, j), sB = __shfl(mySrc, j + 1),
                sC = __shfl(mySrc, j + 2), sD = __shfl(mySrc, j + 3);
            float aA, aB, aC, aD;
            if (TWO) {
                float x0 = __shfl(myA0, j),     y0 = __shfl(myA1, j);
                float x1 = __shfl(myA0, j + 1), y1 = __shfl(myA1, j + 1);
                float x2 = __shfl(myA0, j + 2), y2 = __shfl(myA1, j + 2);
                float x3 = __shfl(myA0, j + 3), y3 = __shfl(myA1, j + 3);
                bool up = (lane >= 32);
                aA = up ? y0 : x0; aB = up ? y1 : x1;
                aC = up ? y2 : x2; aD = up ? y3 : x3;
            } else {
                aA = __shfl(myA0, j);     aB = __shfl(myA0, j + 1);
                aC = __shfl(myA0, j + 2); aD = __shfl(myA0, j + 3);
            }
            uint2 gA = *(const uint2*)(h + (size_t)sA * HC + c0);
            uint2 gB = *(const uint2*)(h + (size_t)sB * HC + c0);
            uint2 gC = *(const uint2*)(h + (size_t)sC * HC + c0);
            uint2 gD = *(const uint2*)(h + (size_t)sD * HC + c0);
            acc0[0] += aA * bf2f((u16)(gA.x & 0xffff));
            acc0[1] += aA * bf2f((u16)(gA.x >> 16));
            acc0[2] += aA * bf2f((u16)(gA.y & 0xffff));
            acc0[3] += aA * bf2f((u16)(gA.y >> 16));
            acc1[0] += aB * bf2f((u16)(gB.x & 0xffff));
            acc1[1] += aB * bf2f((u16)(gB.x >> 16));
            acc1[2] += aB * bf2f((u16)(gB.y & 0xffff));
            acc1[3] += aB * bf2f((u16)(gB.y >> 16));
            acc2[0] += aC * bf2f((u16)(gC.x & 0xffff));
            acc2[1] += aC * bf2f((u16)(gC.x >> 16));
            acc2[2] += aC * bf2f((u16)(gC.y & 0xffff));
            acc2[3] += aC * bf2f((u16)(gC.y >> 16));
            acc3[0] += aD * bf2f((u16)(gD.x & 0xffff));
            acc3[1] += aD * bf2f((u16)(gD.x >> 16));
            acc3[2] += aD * bf2f((u16)(gD.y & 0xffff));
            acc3[3] += aD * bf2f((u16)(gD.y >> 16));
        }
        for (; j < cnt; ++j) {
            int sA = __shfl(mySrc, j);
            float aA;
            if (TWO) {
                float x0 = __shfl(myA0, j), y0 = __shfl(myA1, j);
                aA = (lane >= 32) ? y0 : x0;
            } else {
                aA = __shfl(myA0, j);
            }
            uint2 gA = *(const uint2*)(h + (size_t)sA * HC + c0);
            acc0[0] += aA * bf2f((u16)(gA.x & 0xffff));
            acc0[1] += aA * bf2f((u16)(gA.x >> 16));
            acc0[2] += aA * bf2f((u16)(gA.y & 0xffff));
            acc0[3] += aA * bf2f((u16)(gA.y >> 16));
        }
    }

    float sc = inv[(size_t)d * H + hd];
    u16 os[4];
#pragma unroll
    for (int k = 0; k < 4; ++k) {
        float v = (acc0[k] + acc1[k]) + (acc2[k] + acc3[k]);
        v = v * sc + bias[c0 + k];
        if (ACT == 1) v = (v > 0.f) ? v : (expf(v) - 1.f);  // elu
        else          v = fmaxf(v, 0.f);                     // relu
        os[k] = f2bf(v);
    }
    uint2 q;
    q.x = (u32)os[0] | ((u32)os[1] << 16);
    q.y = (u32)os[2] | ((u32)os[3] << 16);
    *(uint2*)(out + (size_t)d * HC + c0) = q;
}

extern "C" void kernel_launch(void* const* d_in, const int* in_sizes, int n_in,
                              void* d_out, int out_size, void* d_ws, size_t ws_size,
                              hipStream_t stream) {
    const float* node      = (const float*)d_in[0];
    const int*   esrc      = (const int*)d_in[1];          // edge_index[0]
    const int*   edst      = ((const int*)d_in[1]) + EE;   // edge_index[1]
    const float* W1        = (const float*)d_in[2];
    const float* att_src1  = (const float*)d_in[3];
    const float* att_dst1  = (const float*)d_in[4];
    const float* b1        = (const float*)d_in[5];
    const float* W2        = (const float*)d_in[6];
    const float* att_src2  = (const float*)d_in[7];
    const float* att_dst2  = (const float*)d_in[8];
    const float* b2        = (const float*)d_in[9];
    const float* fc_w      = (const float*)d_in[10];
    const float* fc_b      = (const float*)d_in[11];
    float* out = (float*)d_out;

    // ---- workspace layout ----
    u16* bufA  = (u16*)d_ws;                        // [NN*HC1]  h1b, later h2b
    u16* bufB  = bufA + (size_t)NN * HC1;           // [NN*HC1]  x2b, later out2b
    u16* nodeb = bufB + (size_t)NN * HC1;           // [NN*F_IN]
    u16* w1t   = nodeb + (size_t)NN * F_IN;         // [HC1*F_IN]
    u16* w2t   = w1t + (size_t)HC1 * F_IN;          // [HC2*HC1]
    u16* fcwt  = w2t + (size_t)HC2 * HC1;           // [OUT_DIM*OUT_DIM]
    float* exal  = (float*)(fcwt + (size_t)OUT_DIM * OUT_DIM);  // [ETOT*H1]
    float* inv   = exal + (size_t)ETOT * H1;        // [NN*H1]
    float* a_s1  = inv + (size_t)NN * H1;           // [NN*H1]
    float* a_d1  = a_s1 + (size_t)NN * H1;
    float* a_s2  = a_d1 + (size_t)NN * H1;          // [NN]
    float* a_d2  = a_s2 + NN;
    int* deg       = (int*)(a_d2 + NN);
    int* cursor    = deg + NN;
    int* row_start = cursor + NN;                   // [NN+1]
    int* slot_src  = row_start + NN + 8;            // [ETOT]

    // ---- conversions ----
    f32_to_bf16_kernel<<<(NN * F_IN + 255) / 256, 256, 0, stream>>>(node, nodeb, NN * F_IN);
    transpose_bf16_kernel<<<dim3(HC1 / 16, F_IN / 16), dim3(16, 16), 0, stream>>>(W1, w1t, F_IN, HC1);
    transpose_bf16_kernel<<<dim3(HC2 / 16, HC1 / 16), dim3(16, 16), 0, stream>>>(W2, w2t, HC1, HC2);
    transpose_bf16_kernel<<<dim3(OUT_DIM / 16, OUT_DIM / 16), dim3(16, 16), 0, stream>>>(fc_w, fcwt, OUT_DIM, OUT_DIM);

    // ---- CSR build ----
    hipMemsetAsync(deg, 0, 2 * NN * sizeof(int), stream);  // deg + cursor
    hist_kernel<<<(ETOT + 255) / 256, 256, 0, stream>>>(edst, deg);
    scan_kernel<<<1, 1024, 0, stream>>>(deg, row_start);
    fill_kernel<<<(ETOT + 255) / 256, 256, 0, stream>>>(esrc, edst, row_start, cursor, slot_src);

    // ---- layer 1 ----
    gemm_bf16<0><<<dim3(HC1 / 128, (NN + 127) / 128), 256, 0, stream>>>(nodeb, w1t, nullptr, bufA, NN, HC1, F_IN);
    att_logits2<H1, C1><<<NN / 2, 128, 0, stream>>>(bufA, att_src1, att_dst1, a_s1, a_d1);
    att_alpha2<H1><<<NN / 2, 128, 0, stream>>>(row_start, slot_src, a_s1, a_d1, exal, inv);
    gat_scatter4<1, H1, C1, 256><<<dim3(NN / 2, HC1 / 256), 128, 0, stream>>>(row_start, slot_src, exal, inv, bufA, b1, bufB);

    // ---- layer 2 ----
    gemm_bf16<0><<<dim3(HC2 / 128, (NN + 127) / 128), 256, 0, stream>>>(bufB, w2t, nullptr, bufA, NN, HC2, HC1);
    att_logits2<H2, C2><<<NN / 2, 128, 0, stream>>>(bufA, att_src2, att_dst2, a_s2, a_d2);
    att_alpha2<H2><<<NN / 2, 128, 0, stream>>>(row_start, slot_src, a_s2, a_d2, exal, inv);
    gat_scatter4<2, H2, C2, 256><<<dim3(NN / 2, HC2 / 256), 128, 0, stream>>>(row_start, slot_src, exal, inv, bufA, b2, bufB);

    // ---- fc: out = relu(out2 @ fc_w + fc_b), f32 out ----
    gemm_bf16<1><<<dim3(OUT_DIM / 128, (NN + 127) / 128), 256, 0, stream>>>(bufB, fcwt, fc_b, out, NN, OUT_DIM, OUT_DIM);
}

// Round 5
// 254.728 us; speedup vs baseline: 1.3176x; 1.0651x over previous
//
#include <hip/hip_runtime.h>
#include <hip/hip_bf16.h>
#include <cstddef>
#include <cstdint>

// Problem constants
#define NN 10000
#define EE 160000
#define ETOT (EE + NN)
#define F_IN 128
#define H1 10
#define C1 128
#define HC1 1280
#define H2 1
#define C2 1024
#define HC2 1024
#define OUT_DIM 1024

typedef __attribute__((ext_vector_type(4))) float f32x4;
typedef __attribute__((ext_vector_type(8))) short s16x8;
typedef unsigned int u32;
typedef unsigned short u16;

__device__ __forceinline__ float bf2f(u16 v) {
    union { u32 u; float f; } x; x.u = ((u32)v) << 16; return x.f;
}
__device__ __forceinline__ u16 f2bf(float f) {
    union { float f; u32 u; } x; x.f = f;
    u32 u = x.u;
    u32 r = (u + 0x7fffu + ((u >> 16) & 1u)) >> 16;   // RNE
    return (u16)r;
}

__device__ __forceinline__ void gld16(const void* g, void* l) {
    __builtin_amdgcn_global_load_lds((const __attribute__((address_space(1))) u32*)g,
                                     (__attribute__((address_space(3))) u32*)l, 16, 0, 0);
}

// ---------------- conversions ----------------
__global__ void f32_to_bf16_kernel(const float* __restrict__ in, u16* __restrict__ out, int n) {
    int i = blockIdx.x * 256 + threadIdx.x;
    if (i < n) out[i] = f2bf(in[i]);
}

// in: [K][N] row-major f32; out: [N][K] bf16. K,N multiples of 16. Coalesced both sides.
__global__ void transpose_bf16_kernel(const float* __restrict__ in, u16* __restrict__ out,
                                      int K, int N) {
    __shared__ u16 t[16][17];
    int n0 = blockIdx.x * 16, k0 = blockIdx.y * 16;
    t[threadIdx.y][threadIdx.x] = f2bf(in[(size_t)(k0 + threadIdx.y) * N + n0 + threadIdx.x]);
    __syncthreads();
    out[(size_t)(n0 + threadIdx.y) * K + k0 + threadIdx.x] = t[threadIdx.x][threadIdx.y];
}

// ---------------- CSR build ----------------
__global__ void hist_kernel(const int* __restrict__ edst, int* __restrict__ deg) {
    int e = blockIdx.x * 256 + threadIdx.x;
    if (e >= ETOT) return;
    int d = (e < EE) ? edst[e] : (e - EE);
    atomicAdd(&deg[d], 1);
}

// shfl-based single-block scan (1024 threads)
__global__ void scan_kernel(const int* __restrict__ deg, int* __restrict__ row_start) {
    __shared__ int wsum[16];
    const int tid = threadIdx.x;
    const int lane = tid & 63;
    const int wid = tid >> 6;
    int carry = 0;
    for (int base = 0; base < NN; base += 1024) {
        int i = base + tid;
        int v = (i < NN) ? deg[i] : 0;
        int x = v;
#pragma unroll
        for (int o = 1; o < 64; o <<= 1) {
            int t = __shfl_up(x, o);
            if (lane >= o) x += t;
        }
        if (lane == 63) wsum[wid] = x;
        __syncthreads();
        if (wid == 0) {
            int w = (lane < 16) ? wsum[lane] : 0;
#pragma unroll
            for (int o = 1; o < 16; o <<= 1) {
                int t = __shfl_up(w, o);
                if (lane >= o) w += t;
            }
            if (lane < 16) wsum[lane] = w;
        }
        __syncthreads();
        int woff = (wid == 0) ? 0 : wsum[wid - 1];
        if (i < NN) row_start[i] = carry + woff + x - v;   // exclusive
        carry += wsum[15];
        __syncthreads();
    }
    if (tid == 0) row_start[NN] = carry;
}

__global__ void fill_kernel(const int* __restrict__ esrc, const int* __restrict__ edst,
                            const int* __restrict__ row_start, int* __restrict__ cursor,
                            int* __restrict__ slot_src) {
    int e = blockIdx.x * 256 + threadIdx.x;
    if (e >= ETOT) return;
    int s, d;
    if (e < EE) { s = esrc[e]; d = edst[e]; }
    else        { s = d = e - EE; }
    int pos = atomicAdd(&cursor[d], 1);
    slot_src[row_start[d] + pos] = s;
}

// ---------------- bf16 MFMA GEMM: C = A[MxK] * Bt[NxK]^T ----------------
// 128x128 tile, 4 waves, 16x16x32 MFMA, BK=32.
// 2-phase double-buffered LDS: prefetch tile t+1 issued BEFORE compute of tile t.
// XCD-aware bijective block swizzle (m204): each XCD gets a contiguous bm chunk.
template<int BIAS_RELU>
__global__ __launch_bounds__(256, 2)
void gemm_bf16(const u16* __restrict__ A, const u16* __restrict__ Bt,
               const float* __restrict__ bias, void* __restrict__ Cout,
               int M, int N, int K) {
    __shared__ u16 Als[2][128 * 32];
    __shared__ u16 Bls[2][128 * 32];
    const int tid  = threadIdx.x;
    const int wave = tid >> 6;
    const int lane = tid & 63;

    // bijective XCD swizzle
    const int nwg = gridDim.x * gridDim.y;
    const int bid = blockIdx.y * gridDim.x + blockIdx.x;
    const int q = nwg >> 3, r = nwg & 7;
    const int xcd = bid & 7, idx = bid >> 3;
    const int swz = (xcd < r ? xcd * (q + 1) : r * (q + 1) + (xcd - r) * q) + idx;
    const int bm = (swz / gridDim.x) * 128;
    const int bn = (swz % gridDim.x) * 128;

    const int wr = wave >> 1, wc = wave & 1;   // 2x2 waves, each 64x64
    const int lr = lane & 15;
    const int kc = lane >> 4;

    f32x4 acc[4][4] = {};

    const int srow = tid >> 2;
    const int scol = (tid & 3) * 8;
    int arow0 = bm + srow;       if (arow0 >= M) arow0 = M - 1;
    int arow1 = bm + 64 + srow;  if (arow1 >= M) arow1 = M - 1;
    const int brow0 = bn + srow;
    const int brow1 = bn + 64 + srow;

    const u16* aP0 = A  + (size_t)arow0 * K + scol;
    const u16* aP1 = A  + (size_t)arow1 * K + scol;
    const u16* bP0 = Bt + (size_t)brow0 * K + scol;
    const u16* bP1 = Bt + (size_t)brow1 * K + scol;

    // prologue: stage tile 0 into buf 0
    gld16(aP0, &Als[0][(size_t)wave * 512]);
    gld16(aP1, &Als[0][2048 + (size_t)wave * 512]);
    gld16(bP0, &Bls[0][(size_t)wave * 512]);
    gld16(bP1, &Bls[0][2048 + (size_t)wave * 512]);
    __syncthreads();

    int cur = 0;
    for (int k0 = 0; k0 < K; k0 += 32) {
        // issue prefetch of next tile into the other buffer (overlaps with MFMA below)
        if (k0 + 32 < K) {
            int nxt = cur ^ 1;
            gld16(aP0 + k0 + 32, &Als[nxt][(size_t)wave * 512]);
            gld16(aP1 + k0 + 32, &Als[nxt][2048 + (size_t)wave * 512]);
            gld16(bP0 + k0 + 32, &Bls[nxt][(size_t)wave * 512]);
            gld16(bP1 + k0 + 32, &Bls[nxt][2048 + (size_t)wave * 512]);
        }

        s16x8 af[4], bg[4];
#pragma unroll
        for (int i = 0; i < 4; ++i)
            af[i] = *(const s16x8*)&Als[cur][(wr * 64 + i * 16 + lr) * 32 + kc * 8];
#pragma unroll
        for (int j = 0; j < 4; ++j)
            bg[j] = *(const s16x8*)&Bls[cur][(wc * 64 + j * 16 + lr) * 32 + kc * 8];
#pragma unroll
        for (int i = 0; i < 4; ++i)
#pragma unroll
            for (int j = 0; j < 4; ++j)
                acc[i][j] = __builtin_amdgcn_mfma_f32_16x16x32_bf16(af[i], bg[j], acc[i][j], 0, 0, 0);

        __syncthreads();   // drains vmcnt (prefetch landed) + lgkm; safe to swap
        cur ^= 1;
    }

    // C/D layout: col = lane&15, row = (lane>>4)*4 + reg
#pragma unroll
    for (int i = 0; i < 4; ++i) {
#pragma unroll
        for (int r2 = 0; r2 < 4; ++r2) {
            int m = bm + wr * 64 + i * 16 + kc * 4 + r2;
            if (m >= M) continue;
#pragma unroll
            for (int j = 0; j < 4; ++j) {
                int n = bn + wc * 64 + j * 16 + lr;
                float v = acc[i][j][r2];
                if (BIAS_RELU) {
                    v += bias[n];
                    v = fmaxf(v, 0.f);
                    ((float*)Cout)[(size_t)m * N + n] = v;
                } else {
                    ((u16*)Cout)[(size_t)m * N + n] = f2bf(v);
                }
            }
        }
    }
}

// ---------------- logits v2: one block = 2 nodes, head loop inside ----------------
template<int H, int C>
__global__ __launch_bounds__(128)
void att_logits2(const u16* __restrict__ h, const float* __restrict__ att_s,
                 const float* __restrict__ att_d, float* __restrict__ a_s,
                 float* __restrict__ a_d) {
    const int n = blockIdx.x * 2 + (threadIdx.x >> 6);
    const int lane = threadIdx.x & 63;
    const u16* row = h + (size_t)n * H * C;
#pragma unroll
    for (int hd = 0; hd < H; ++hd) {
        float ps = 0.f, pd = 0.f;
        for (int c = lane * 2; c < C; c += 128) {
            u32 q = *(const u32*)(row + hd * C + c);
            float v0 = bf2f((u16)(q & 0xffff));
            float v1 = bf2f((u16)(q >> 16));
            float2 s = *(const float2*)(att_s + hd * C + c);
            float2 dd = *(const float2*)(att_d + hd * C + c);
            ps += v0 * s.x + v1 * s.y;
            pd += v0 * dd.x + v1 * dd.y;
        }
#pragma unroll
        for (int off = 32; off; off >>= 1) {
            ps += __shfl_down(ps, off);
            pd += __shfl_down(pd, off);
        }
        if (lane == 0) {
            a_s[n * H + hd] = ps;
            a_d[n * H + hd] = pd;
        }
    }
}

// ---------------- alpha v2: unnormalized exp + per-(d,h) inverse sum ----------------
template<int H>
__global__ __launch_bounds__(128)
void att_alpha2(const int* __restrict__ row_start, const int* __restrict__ slot_src,
                const float* __restrict__ a_s, const float* __restrict__ a_d,
                float* __restrict__ exal, float* __restrict__ inv) {
    const int d = blockIdx.x * 2 + (threadIdx.x >> 6);
    const int lane = threadIdx.x & 63;
    const int s0 = row_start[d], s1 = row_start[d + 1];
    float ad[H];
#pragma unroll
    for (int hd = 0; hd < H; ++hd) ad[hd] = a_d[(size_t)d * H + hd];
    float sums[H];
#pragma unroll
    for (int hd = 0; hd < H; ++hd) sums[hd] = 0.f;

    for (int base = s0; base < s1; base += 64) {
        int e = base + lane;
        bool ok = (e < s1);
        int src = ok ? slot_src[e] : 0;
        float as[H];
        if constexpr (H == 1) {
            as[0] = ok ? a_s[src] : 0.f;
        } else {
            const float2* asp = (const float2*)(a_s + (size_t)src * H);
#pragma unroll
            for (int i = 0; i < H / 2; ++i) {
                float2 q = ok ? asp[i] : make_float2(0.f, 0.f);
                as[2 * i] = q.x; as[2 * i + 1] = q.y;
            }
        }
        float ex[H];
#pragma unroll
        for (int hd = 0; hd < H; ++hd) {
            float t = as[hd] + ad[hd];
            t = (t > 0.f) ? t : 0.2f * t;          // leaky_relu 0.2
            float x = ok ? expf(t) : 0.f;          // logits small by construction
            ex[hd] = x;
            sums[hd] += x;
        }
        if (ok) {
            if constexpr (H == 1) {
                exal[e] = ex[0];
            } else {
                float2* op = (float2*)(exal + (size_t)e * H);
#pragma unroll
                for (int i = 0; i < H / 2; ++i) op[i] = make_float2(ex[2 * i], ex[2 * i + 1]);
            }
        }
    }
#pragma unroll
    for (int hd = 0; hd < H; ++hd) {
#pragma unroll
        for (int off = 32; off; off >>= 1) sums[hd] += __shfl_down(sums[hd], off);
    }
    if (lane == 0) {
#pragma unroll
        for (int hd = 0; hd < H; ++hd) inv[(size_t)d * H + hd] = 1.f / (sums[hd] + 1e-16f);
    }
}

// ---------------- scatter v4: segment-major, shfl-broadcast metadata, 4-deep ILP ----
template<int ACT, int H, int C, int SEG>
__global__ __launch_bounds__(128)
void gat_scatter4(const int* __restrict__ row_start, const int* __restrict__ slot_src,
                  const float* __restrict__ exal, const float* __restrict__ inv,
                  const u16* __restrict__ h, const float* __restrict__ bias,
                  u16* __restrict__ out) {
    constexpr int HC = H * C;
    constexpr bool TWO = (SEG == 2 * C);   // segment spans 2 heads (layer 1)
    const int d = blockIdx.x * 2 + (threadIdx.x >> 6);
    const int lane = threadIdx.x & 63;
    const int c0 = blockIdx.y * SEG + lane * 4;
    const int hd = c0 / C;
    const int hA = (blockIdx.y * SEG) / C;
    const int s0 = row_start[d], s1 = row_start[d + 1];

    float acc0[4] = {}, acc1[4] = {}, acc2[4] = {}, acc3[4] = {};

    for (int base = s0; base < s1; base += 64) {
        int e = base + lane;
        bool ok = (e < s1);
        int mySrc = 0; float myA0 = 0.f, myA1 = 0.f;
        if (ok) {
            mySrc = slot_src[e];
            myA0 = exal[(size_t)e * H + hA];
            if (TWO) myA1 = exal[(size_t)e * H + hA + 1];
        }
        int cnt = min(64, s1 - base);
        int j = 0;
        for (; j + 4 <= cnt; j += 4) {
            int sA = __shfl(mySrc, j), sB = __shfl(mySrc, j + 1),
                sC = __shfl(mySrc, j + 2), sD = __shfl(mySrc, j + 3);
            float aA, aB, aC, aD;
            if (TWO) {
                float x0 = __shfl(myA0, j),     y0 = __shfl(myA1, j);
                float x1 = __shfl(myA0, j + 1), y1 = __shfl(myA1, j + 1);
                float x2 = __shfl(myA0, j + 2), y2 = __shfl(myA1, j + 2);
                float x3 = __shfl(myA0, j + 3), y3 = __shfl(myA1, j + 3);
                bool up = (lane >= 32);
                aA = up ? y0 : x0; aB = up ? y1 : x1;
                aC = up ? y2 : x2; aD = up ? y3 : x3;
            } else {
                aA = __shfl(myA0, j);     aB = __shfl(myA0, j + 1);
                aC = __shfl(myA0, j + 2); aD = __shfl(myA0, j + 3);
            }
            uint2 gA = *(const uint2*)(h + (size_t)sA * HC + c0);
            uint2 gB = *(const uint2*)(h + (size_t)sB * HC + c0);
            uint2 gC = *(const uint2*)(h + (size_t)sC * HC + c0);
            uint2 gD = *(const uint2*)(h + (size_t)sD * HC + c0);
            acc0[0] += aA * bf2f((u16)(gA.x & 0xffff));
            acc0[1] += aA * bf2f((u16)(gA.x >> 16));
            acc0[2] += aA * bf2f((u16)(gA.y & 0xffff));
            acc0[3] += aA * bf2f((u16)(gA.y >> 16));
            acc1[0] += aB * bf2f((u16)(gB.x & 0xffff));
            acc1[1] += aB * bf2f((u16)(gB.x >> 16));
            acc1[2] += aB * bf2f((u16)(gB.y & 0xffff));
            acc1[3] += aB * bf2f((u16)(gB.y >> 16));
            acc2[0] += aC * bf2f((u16)(gC.x & 0xffff));
            acc2[1] += aC * bf2f((u16)(gC.x >> 16));
            acc2[2] += aC * bf2f((u16)(gC.y & 0xffff));
            acc2[3] += aC * bf2f((u16)(gC.y >> 16));
            acc3[0] += aD * bf2f((u16)(gD.x & 0xffff));
            acc3[1] += aD * bf2f((u16)(gD.x >> 16));
            acc3[2] += aD * bf2f((u16)(gD.y & 0xffff));
            acc3[3] += aD * bf2f((u16)(gD.y >> 16));
        }
        for (; j < cnt; ++j) {
            int sA = __shfl(mySrc, j);
            float aA;
            if (TWO) {
                float x0 = __shfl(myA0, j), y0 = __shfl(myA1, j);
                aA = (lane >= 32) ? y0 : x0;
            } else {
                aA = __shfl(myA0, j);
            }
            uint2 gA = *(const uint2*)(h + (size_t)sA * HC + c0);
            acc0[0] += aA * bf2f((u16)(gA.x & 0xffff));
            acc0[1] += aA * bf2f((u16)(gA.x >> 16));
            acc0[2] += aA * bf2f((u16)(gA.y & 0xffff));
            acc0[3] += aA * bf2f((u16)(gA.y >> 16));
        }
    }

    float sc = inv[(size_t)d * H + hd];
    u16 os[4];
#pragma unroll
    for (int k = 0; k < 4; ++k) {
        float v = (acc0[k] + acc1[k]) + (acc2[k] + acc3[k]);
        v = v * sc + bias[c0 + k];
        if (ACT == 1) v = (v > 0.f) ? v : (expf(v) - 1.f);  // elu
        else          v = fmaxf(v, 0.f);                     // relu
        os[k] = f2bf(v);
    }
    uint2 q;
    q.x = (u32)os[0] | ((u32)os[1] << 16);
    q.y = (u32)os[2] | ((u32)os[3] << 16);
    *(uint2*)(out + (size_t)d * HC + c0) = q;
}

extern "C" void kernel_launch(void* const* d_in, const int* in_sizes, int n_in,
                              void* d_out, int out_size, void* d_ws, size_t ws_size,
                              hipStream_t stream) {
    const float* node      = (const float*)d_in[0];
    const int*   esrc      = (const int*)d_in[1];          // edge_index[0]
    const int*   edst      = ((const int*)d_in[1]) + EE;   // edge_index[1]
    const float* W1        = (const float*)d_in[2];
    const float* att_src1  = (const float*)d_in[3];
    const float* att_dst1  = (const float*)d_in[4];
    const float* b1        = (const float*)d_in[5];
    const float* W2        = (const float*)d_in[6];
    const float* att_src2  = (const float*)d_in[7];
    const float* att_dst2  = (const float*)d_in[8];
    const float* b2        = (const float*)d_in[9];
    const float* fc_w      = (const float*)d_in[10];
    const float* fc_b      = (const float*)d_in[11];
    float* out = (float*)d_out;

    // ---- workspace layout ----
    u16* bufA  = (u16*)d_ws;                        // [NN*HC1]  h1b, later h2b
    u16* bufB  = bufA + (size_t)NN * HC1;           // [NN*HC1]  x2b, later out2b
    u16* nodeb = bufB + (size_t)NN * HC1;           // [NN*F_IN]
    u16* w1t   = nodeb + (size_t)NN * F_IN;         // [HC1*F_IN]
    u16* w2t   = w1t + (size_t)HC1 * F_IN;          // [HC2*HC1]
    u16* fcwt  = w2t + (size_t)HC2 * HC1;           // [OUT_DIM*OUT_DIM]
    float* exal  = (float*)(fcwt + (size_t)OUT_DIM * OUT_DIM);  // [ETOT*H1]
    float* inv   = exal + (size_t)ETOT * H1;        // [NN*H1]
    float* a_s1  = inv + (size_t)NN * H1;           // [NN*H1]
    float* a_d1  = a_s1 + (size_t)NN * H1;
    float* a_s2  = a_d1 + (size_t)NN * H1;          // [NN]
    float* a_d2  = a_s2 + NN;
    int* deg       = (int*)(a_d2 + NN);
    int* cursor    = deg + NN;
    int* row_start = cursor + NN;                   // [NN+1]
    int* slot_src  = row_start + NN + 8;            // [ETOT]

    // ---- conversions ----
    f32_to_bf16_kernel<<<(NN * F_IN + 255) / 256, 256, 0, stream>>>(node, nodeb, NN * F_IN);
    transpose_bf16_kernel<<<dim3(HC1 / 16, F_IN / 16), dim3(16, 16), 0, stream>>>(W1, w1t, F_IN, HC1);
    transpose_bf16_kernel<<<dim3(HC2 / 16, HC1 / 16), dim3(16, 16), 0, stream>>>(W2, w2t, HC1, HC2);
    transpose_bf16_kernel<<<dim3(OUT_DIM / 16, OUT_DIM / 16), dim3(16, 16), 0, stream>>>(fc_w, fcwt, OUT_DIM, OUT_DIM);

    // ---- CSR build ----
    hipMemsetAsync(deg, 0, 2 * NN * sizeof(int), stream);  // deg + cursor
    hist_kernel<<<(ETOT + 255) / 256, 256, 0, stream>>>(edst, deg);
    scan_kernel<<<1, 1024, 0, stream>>>(deg, row_start);
    fill_kernel<<<(ETOT + 255) / 256, 256, 0, stream>>>(esrc, edst, row_start, cursor, slot_src);

    // ---- layer 1 ----
    gemm_bf16<0><<<dim3(HC1 / 128, (NN + 127) / 128), 256, 0, stream>>>(nodeb, w1t, nullptr, bufA, NN, HC1, F_IN);
    att_logits2<H1, C1><<<NN / 2, 128, 0, stream>>>(bufA, att_src1, att_dst1, a_s1, a_d1);
    att_alpha2<H1><<<NN / 2, 128, 0, stream>>>(row_start, slot_src, a_s1, a_d1, exal, inv);
    gat_scatter4<1, H1, C1, 256><<<dim3(NN / 2, HC1 / 256), 128, 0, stream>>>(row_start, slot_src, exal, inv, bufA, b1, bufB);

    // ---- layer 2 ----
    gemm_bf16<0><<<dim3(HC2 / 128, (NN + 127) / 128), 256, 0, stream>>>(bufB, w2t, nullptr, bufA, NN, HC2, HC1);
    att_logits2<H2, C2><<<NN / 2, 128, 0, stream>>>(bufA, att_src2, att_dst2, a_s2, a_d2);
    att_alpha2<H2><<<NN / 2, 128, 0, stream>>>(row_start, slot_src, a_s2, a_d2, exal, inv);
    gat_scatter4<2, H2, C2, 256><<<dim3(NN / 2, HC2 / 256), 128, 0, stream>>>(row_start, slot_src, exal, inv, bufA, b2, bufB);

    // ---- fc: out = relu(out2 @ fc_w + fc_b), f32 out ----
    gemm_bf16<1><<<dim3(OUT_DIM / 128, (NN + 127) / 128), 256, 0, stream>>>(bufB, fcwt, fc_b, out, NN, OUT_DIM, OUT_DIM);
}

// Round 7
// 249.419 us; speedup vs baseline: 1.3456x; 1.0213x over previous
//
#include <hip/hip_runtime.h>
#include <hip/hip_bf16.h>
#include <cstddef>
#include <cstdint>

// Problem constants
#define NN 10000
#define EE 160000
#define ETOT (EE + NN)
#define F_IN 128
#define H1 10
#define C1 128
#define HC1 1280
#define H2 1
#define C2 1024
#define HC2 1024
#define OUT_DIM 1024

typedef __attribute__((ext_vector_type(4))) float f32x4;
typedef __attribute__((ext_vector_type(8))) short s16x8;
typedef unsigned int u32;
typedef unsigned short u16;

__device__ __forceinline__ float bf2f(u16 v) {
    union { u32 u; float f; } x; x.u = ((u32)v) << 16; return x.f;
}
__device__ __forceinline__ float bflo(u32 q) {   // low bf16 of a packed u32
    union { u32 u; float f; } x; x.u = q << 16; return x.f;
}
__device__ __forceinline__ float bfhi(u32 q) {   // high bf16 of a packed u32
    union { u32 u; float f; } x; x.u = q & 0xffff0000u; return x.f;
}
__device__ __forceinline__ u16 f2bf(float f) {
    union { float f; u32 u; } x; x.f = f;
    u32 u = x.u;
    u32 r = (u + 0x7fffu + ((u >> 16) & 1u)) >> 16;   // RNE
    return (u16)r;
}

__device__ __forceinline__ void gld16(const void* g, void* l) {
    __builtin_amdgcn_global_load_lds((const __attribute__((address_space(1))) u32*)g,
                                     (__attribute__((address_space(3))) u32*)l, 16, 0, 0);
}

// Producer-side drain of async global_load_lds BEFORE the barrier.
// Required for cross-wave visibility: each wave's gld16 is tracked only by its
// own vmcnt; without this the compiler may sink the wait past the barrier to
// the issuing wave's own ds_read, letting OTHER waves read stale LDS (the
// post-timing divergence seen in round 6).
__device__ __forceinline__ void vm_drain() {
    asm volatile("s_waitcnt vmcnt(0)" ::: "memory");
}

// ---------------- conversions ----------------
__global__ void f32_to_bf16_kernel(const float* __restrict__ in, u16* __restrict__ out, int n) {
    int i = blockIdx.x * 256 + threadIdx.x;
    if (i < n) out[i] = f2bf(in[i]);
}

// in: [K][N] row-major f32; out: [N][K] bf16. K,N multiples of 16. Coalesced both sides.
__global__ void transpose_bf16_kernel(const float* __restrict__ in, u16* __restrict__ out,
                                      int K, int N) {
    __shared__ u16 t[16][17];
    int n0 = blockIdx.x * 16, k0 = blockIdx.y * 16;
    t[threadIdx.y][threadIdx.x] = f2bf(in[(size_t)(k0 + threadIdx.y) * N + n0 + threadIdx.x]);
    __syncthreads();
    out[(size_t)(n0 + threadIdx.y) * K + k0 + threadIdx.x] = t[threadIdx.x][threadIdx.y];
}

// ---------------- CSR build ----------------
__global__ void hist_kernel(const int* __restrict__ edst, int* __restrict__ deg) {
    int e = blockIdx.x * 256 + threadIdx.x;
    if (e >= ETOT) return;
    int d = (e < EE) ? edst[e] : (e - EE);
    atomicAdd(&deg[d], 1);
}

// shfl-based single-block scan (1024 threads)
__global__ void scan_kernel(const int* __restrict__ deg, int* __restrict__ row_start) {
    __shared__ int wsum[16];
    const int tid = threadIdx.x;
    const int lane = tid & 63;
    const int wid = tid >> 6;
    int carry = 0;
    for (int base = 0; base < NN; base += 1024) {
        int i = base + tid;
        int v = (i < NN) ? deg[i] : 0;
        int x = v;
#pragma unroll
        for (int o = 1; o < 64; o <<= 1) {
            int t = __shfl_up(x, o);
            if (lane >= o) x += t;
        }
        if (lane == 63) wsum[wid] = x;
        __syncthreads();
        if (wid == 0) {
            int w = (lane < 16) ? wsum[lane] : 0;
#pragma unroll
            for (int o = 1; o < 16; o <<= 1) {
                int t = __shfl_up(w, o);
                if (lane >= o) w += t;
            }
            if (lane < 16) wsum[lane] = w;
        }
        __syncthreads();
        int woff = (wid == 0) ? 0 : wsum[wid - 1];
        if (i < NN) row_start[i] = carry + woff + x - v;   // exclusive
        carry += wsum[15];
        __syncthreads();
    }
    if (tid == 0) row_start[NN] = carry;
}

__global__ void fill_kernel(const int* __restrict__ esrc, const int* __restrict__ edst,
                            const int* __restrict__ row_start, int* __restrict__ cursor,
                            int* __restrict__ slot_src) {
    int e = blockIdx.x * 256 + threadIdx.x;
    if (e >= ETOT) return;
    int s, d;
    if (e < EE) { s = esrc[e]; d = edst[e]; }
    else        { s = d = e - EE; }
    int pos = atomicAdd(&cursor[d], 1);
    slot_src[row_start[d] + pos] = s;
}

// ---------------- bf16 MFMA GEMM: C = A[MxK] * Bt[NxK]^T ----------------
// 128x128 tile, 4 waves, 16x16x32 MFMA, BK=32, double-buffered LDS prefetch
// with EXPLICIT producer vmcnt drain before each barrier (race fix),
// bijective XCD swizzle.
template<int BIAS_RELU>
__global__ __launch_bounds__(256, 2)
void gemm_bf16(const u16* __restrict__ A, const u16* __restrict__ Bt,
               const float* __restrict__ bias, void* __restrict__ Cout,
               int M, int N, int K) {
    __shared__ u16 Als[2][128 * 32];
    __shared__ u16 Bls[2][128 * 32];
    const int tid  = threadIdx.x;
    const int wave = tid >> 6;
    const int lane = tid & 63;

    // bijective XCD swizzle
    const int nwg = gridDim.x * gridDim.y;
    const int bid = blockIdx.y * gridDim.x + blockIdx.x;
    const int q = nwg >> 3, r = nwg & 7;
    const int xcd = bid & 7, idx = bid >> 3;
    const int swz = (xcd < r ? xcd * (q + 1) : r * (q + 1) + (xcd - r) * q) + idx;
    const int bm = (swz / gridDim.x) * 128;
    const int bn = (swz % gridDim.x) * 128;

    const int wr = wave >> 1, wc = wave & 1;   // 2x2 waves, each 64x64
    const int lr = lane & 15;
    const int kc = lane >> 4;

    f32x4 acc[4][4] = {};

    const int srow = tid >> 2;
    const int scol = (tid & 3) * 8;
    int arow0 = bm + srow;       if (arow0 >= M) arow0 = M - 1;
    int arow1 = bm + 64 + srow;  if (arow1 >= M) arow1 = M - 1;
    const int brow0 = bn + srow;
    const int brow1 = bn + 64 + srow;

    const u16* aP0 = A  + (size_t)arow0 * K + scol;
    const u16* aP1 = A  + (size_t)arow1 * K + scol;
    const u16* bP0 = Bt + (size_t)brow0 * K + scol;
    const u16* bP1 = Bt + (size_t)brow1 * K + scol;

    // prologue: stage tile 0 into buf 0
    gld16(aP0, &Als[0][(size_t)wave * 512]);
    gld16(aP1, &Als[0][2048 + (size_t)wave * 512]);
    gld16(bP0, &Bls[0][(size_t)wave * 512]);
    gld16(bP1, &Bls[0][2048 + (size_t)wave * 512]);
    vm_drain();          // all our async LDS writes landed before barrier
    __syncthreads();

    int cur = 0;
    for (int k0 = 0; k0 < K; k0 += 32) {
        if (k0 + 32 < K) {
            int nxt = cur ^ 1;
            gld16(aP0 + k0 + 32, &Als[nxt][(size_t)wave * 512]);
            gld16(aP1 + k0 + 32, &Als[nxt][2048 + (size_t)wave * 512]);
            gld16(bP0 + k0 + 32, &Bls[nxt][(size_t)wave * 512]);
            gld16(bP1 + k0 + 32, &Bls[nxt][2048 + (size_t)wave * 512]);
        }

        s16x8 af[4], bg[4];
#pragma unroll
        for (int i = 0; i < 4; ++i)
            af[i] = *(const s16x8*)&Als[cur][(wr * 64 + i * 16 + lr) * 32 + kc * 8];
#pragma unroll
        for (int j = 0; j < 4; ++j)
            bg[j] = *(const s16x8*)&Bls[cur][(wc * 64 + j * 16 + lr) * 32 + kc * 8];
#pragma unroll
        for (int i = 0; i < 4; ++i)
#pragma unroll
            for (int j = 0; j < 4; ++j)
                acc[i][j] = __builtin_amdgcn_mfma_f32_16x16x32_bf16(af[i], bg[j], acc[i][j], 0, 0, 0);

        vm_drain();      // prefetch writes to buf nxt are visible to ALL waves
        __syncthreads();
        cur ^= 1;
    }

    // C/D layout: col = lane&15, row = (lane>>4)*4 + reg
#pragma unroll
    for (int i = 0; i < 4; ++i) {
#pragma unroll
        for (int r2 = 0; r2 < 4; ++r2) {
            int m = bm + wr * 64 + i * 16 + kc * 4 + r2;
            if (m >= M) continue;
#pragma unroll
            for (int j = 0; j < 4; ++j) {
                int n = bn + wc * 64 + j * 16 + lr;
                float v = acc[i][j][r2];
                if (BIAS_RELU) {
                    v += bias[n];
                    v = fmaxf(v, 0.f);
                    ((float*)Cout)[(size_t)m * N + n] = v;
                } else {
                    ((u16*)Cout)[(size_t)m * N + n] = f2bf(v);
                }
            }
        }
    }
}

// ---------------- logits v3: 4 ch/lane vector loads ----------------
template<int H, int C>
__global__ __launch_bounds__(128)
void att_logits3(const u16* __restrict__ h, const float* __restrict__ att_s,
                 const float* __restrict__ att_d, float* __restrict__ a_s,
                 float* __restrict__ a_d) {
    const int n = blockIdx.x * 2 + (threadIdx.x >> 6);
    const int lane = threadIdx.x & 63;
    const u16* row = h + (size_t)n * H * C;
    if constexpr (H == 1) {
        float ps = 0.f, pd = 0.f;
        for (int c = lane * 4; c < C; c += 256) {
            uint2 q = *(const uint2*)(row + c);
            float4 s = *(const float4*)(att_s + c);
            float4 dd = *(const float4*)(att_d + c);
            float v0 = bflo(q.x), v1 = bfhi(q.x), v2 = bflo(q.y), v3 = bfhi(q.y);
            ps += v0 * s.x + v1 * s.y + v2 * s.z + v3 * s.w;
            pd += v0 * dd.x + v1 * dd.y + v2 * dd.z + v3 * dd.w;
        }
#pragma unroll
        for (int off = 32; off; off >>= 1) {
            ps += __shfl_down(ps, off);
            pd += __shfl_down(pd, off);
        }
        if (lane == 0) { a_s[n] = ps; a_d[n] = pd; }
    } else {
        const int sub = lane >> 5;        // which head of the pair
        const int lg  = lane & 31;        // 32 lanes x 4ch = 128 = C
#pragma unroll
        for (int hp = 0; hp < H / 2; ++hp) {
            const int hd = hp * 2 + sub;
            const int c = lg * 4;
            uint2 q = *(const uint2*)(row + hd * C + c);
            float4 s = *(const float4*)(att_s + hd * C + c);
            float4 dd = *(const float4*)(att_d + hd * C + c);
            float v0 = bflo(q.x), v1 = bfhi(q.x), v2 = bflo(q.y), v3 = bfhi(q.y);
            float ps = v0 * s.x + v1 * s.y + v2 * s.z + v3 * s.w;
            float pd = v0 * dd.x + v1 * dd.y + v2 * dd.z + v3 * dd.w;
#pragma unroll
            for (int off = 16; off; off >>= 1) {
                ps += __shfl_down(ps, off, 32);
                pd += __shfl_down(pd, off, 32);
            }
            if (lg == 0) {
                a_s[n * H + hd] = ps;
                a_d[n * H + hd] = pd;
            }
        }
    }
}

// ---------------- alpha v2: unnormalized exp + per-(d,h) inverse sum ----------------
template<int H>
__global__ __launch_bounds__(128)
void att_alpha2(const int* __restrict__ row_start, const int* __restrict__ slot_src,
                const float* __restrict__ a_s, const float* __restrict__ a_d,
                float* __restrict__ exal, float* __restrict__ inv) {
    const int d = blockIdx.x * 2 + (threadIdx.x >> 6);
    const int lane = threadIdx.x & 63;
    const int s0 = row_start[d], s1 = row_start[d + 1];
    float ad[H];
#pragma unroll
    for (int hd = 0; hd < H; ++hd) ad[hd] = a_d[(size_t)d * H + hd];
    float sums[H];
#pragma unroll
    for (int hd = 0; hd < H; ++hd) sums[hd] = 0.f;

    for (int base = s0; base < s1; base += 64) {
        int e = base + lane;
        bool ok = (e < s1);
        int src = ok ? slot_src[e] : 0;
        float as[H];
        if constexpr (H == 1) {
            as[0] = ok ? a_s[src] : 0.f;
        } else {
            const float2* asp = (const float2*)(a_s + (size_t)src * H);
#pragma unroll
            for (int i = 0; i < H / 2; ++i) {
                float2 q = ok ? asp[i] : make_float2(0.f, 0.f);
                as[2 * i] = q.x; as[2 * i + 1] = q.y;
            }
        }
        float ex[H];
#pragma unroll
        for (int hd = 0; hd < H; ++hd) {
            float t = as[hd] + ad[hd];
            t = (t > 0.f) ? t : 0.2f * t;          // leaky_relu 0.2
            float x = ok ? expf(t) : 0.f;          // logits small by construction
            ex[hd] = x;
            sums[hd] += x;
        }
        if (ok) {
            if constexpr (H == 1) {
                exal[e] = ex[0];
            } else {
                float2* op = (float2*)(exal + (size_t)e * H);
#pragma unroll
                for (int i = 0; i < H / 2; ++i) op[i] = make_float2(ex[2 * i], ex[2 * i + 1]);
            }
        }
    }
#pragma unroll
    for (int hd = 0; hd < H; ++hd) {
#pragma unroll
        for (int off = 32; off; off >>= 1) sums[hd] += __shfl_down(sums[hd], off);
    }
    if (lane == 0) {
#pragma unroll
        for (int hd = 0; hd < H; ++hd) inv[(size_t)d * H + hd] = 1.f / (sums[hd] + 1e-16f);
    }
}

// helper: accumulate 8 channels from a uint4 of packed bf16
__device__ __forceinline__ void fma8(float* acc, uint4 g, float a) {
    acc[0] += a * bflo(g.x); acc[1] += a * bfhi(g.x);
    acc[2] += a * bflo(g.y); acc[3] += a * bfhi(g.y);
    acc[4] += a * bflo(g.z); acc[5] += a * bfhi(g.z);
    acc[6] += a * bflo(g.w); acc[7] += a * bfhi(g.w);
}

// ---------------- scatter l1: half-wave groups, 8 ch/lane, 4-deep ILP ----------------
// H=10, C=128, SEG=256 (2 heads per 32-lane group). Block=128 thr = 4 groups.
__global__ __launch_bounds__(128)
void gat_scatter_l1(const int* __restrict__ row_start, const int* __restrict__ slot_src,
                    const float* __restrict__ exal, const float* __restrict__ inv,
                    const u16* __restrict__ h, const float* __restrict__ bias,
                    u16* __restrict__ out) {
    const int grp = threadIdx.x >> 5;     // 0..3
    const int lg  = threadIdx.x & 31;
    const int d = blockIdx.x * 4 + grp;
    const int c0 = blockIdx.y * 256 + lg * 8;
    const int hA = blockIdx.y * 2;
    const int hd = hA + (lg >> 4);
    const int s0 = row_start[d], s1 = row_start[d + 1];

    float acc0[8] = {}, acc1[8] = {}, acc2[8] = {}, acc3[8] = {};

    for (int base = s0; base < s1; base += 32) {
        int e = base + lg;
        bool ok = (e < s1);
        int mySrc = 0; float mA0 = 0.f, mA1 = 0.f;
        if (ok) {
            mySrc = slot_src[e];
            float2 q = *(const float2*)(exal + (size_t)e * H1 + hA);
            mA0 = q.x; mA1 = q.y;
        }
        int cnt = min(32, s1 - base);
        const bool up = (lg >= 16);
        int j = 0;
        for (; j + 4 <= cnt; j += 4) {
            int sA = __shfl(mySrc, j, 32),     sB = __shfl(mySrc, j + 1, 32);
            int sC = __shfl(mySrc, j + 2, 32), sD = __shfl(mySrc, j + 3, 32);
            float x0 = __shfl(mA0, j, 32),     y0 = __shfl(mA1, j, 32);
            float x1 = __shfl(mA0, j + 1, 32), y1 = __shfl(mA1, j + 1, 32);
            float x2 = __shfl(mA0, j + 2, 32), y2 = __shfl(mA1, j + 2, 32);
            float x3 = __shfl(mA0, j + 3, 32), y3 = __shfl(mA1, j + 3, 32);
            float aA = up ? y0 : x0, aB = up ? y1 : x1;
            float aC = up ? y2 : x2, aD = up ? y3 : x3;
            uint4 gA = *(const uint4*)(h + (size_t)sA * HC1 + c0);
            uint4 gB = *(const uint4*)(h + (size_t)sB * HC1 + c0);
            uint4 gC = *(const uint4*)(h + (size_t)sC * HC1 + c0);
            uint4 gD = *(const uint4*)(h + (size_t)sD * HC1 + c0);
            fma8(acc0, gA, aA); fma8(acc1, gB, aB);
            fma8(acc2, gC, aC); fma8(acc3, gD, aD);
        }
        for (; j < cnt; ++j) {
            int sA = __shfl(mySrc, j, 32);
            float x0 = __shfl(mA0, j, 32), y0 = __shfl(mA1, j, 32);
            float aA = up ? y0 : x0;
            uint4 gA = *(const uint4*)(h + (size_t)sA * HC1 + c0);
            fma8(acc0, gA, aA);
        }
    }

    float sc = inv[(size_t)d * H1 + hd];
    float4 b0 = *(const float4*)(bias + c0);
    float4 b1 = *(const float4*)(bias + c0 + 4);
    float bb[8] = { b0.x, b0.y, b0.z, b0.w, b1.x, b1.y, b1.z, b1.w };
    u16 os[8];
#pragma unroll
    for (int k = 0; k < 8; ++k) {
        float v = (acc0[k] + acc1[k]) + (acc2[k] + acc3[k]);
        v = v * sc + bb[k];
        v = (v > 0.f) ? v : (expf(v) - 1.f);   // elu
        os[k] = f2bf(v);
    }
    uint4 q;
    q.x = (u32)os[0] | ((u32)os[1] << 16);
    q.y = (u32)os[2] | ((u32)os[3] << 16);
    q.z = (u32)os[4] | ((u32)os[5] << 16);
    q.w = (u32)os[6] | ((u32)os[7] << 16);
    *(uint4*)(out + (size_t)d * HC1 + c0) = q;
}

// ---------------- scatter l2: wave per dst, 8 ch/lane, 4-deep ILP ----------------
// H=1, C=1024, SEG=512. Block=128 thr = 2 waves.
__global__ __launch_bounds__(128)
void gat_scatter_l2(const int* __restrict__ row_start, const int* __restrict__ slot_src,
                    const float* __restrict__ exal, const float* __restrict__ inv,
                    const u16* __restrict__ h, const float* __restrict__ bias,
                    u16* __restrict__ out) {
    const int d = blockIdx.x * 2 + (threadIdx.x >> 6);
    const int lane = threadIdx.x & 63;
    const int c0 = blockIdx.y * 512 + lane * 8;
    const int s0 = row_start[d], s1 = row_start[d + 1];

    float acc0[8] = {}, acc1[8] = {}, acc2[8] = {}, acc3[8] = {};

    for (int base = s0; base < s1; base += 64) {
        int e = base + lane;
        bool ok = (e < s1);
        int mySrc = 0; float mA = 0.f;
        if (ok) { mySrc = slot_src[e]; mA = exal[e]; }
        int cnt = min(64, s1 - base);
        int j = 0;
        for (; j + 4 <= cnt; j += 4) {
            int sA = __shfl(mySrc, j),     sB = __shfl(mySrc, j + 1);
            int sC = __shfl(mySrc, j + 2), sD = __shfl(mySrc, j + 3);
            float aA = __shfl(mA, j),     aB = __shfl(mA, j + 1);
            float aC = __shfl(mA, j + 2), aD = __shfl(mA, j + 3);
            uint4 gA = *(const uint4*)(h + (size_t)sA * HC2 + c0);
            uint4 gB = *(const uint4*)(h + (size_t)sB * HC2 + c0);
            uint4 gC = *(const uint4*)(h + (size_t)sC * HC2 + c0);
            uint4 gD = *(const uint4*)(h + (size_t)sD * HC2 + c0);
            fma8(acc0, gA, aA); fma8(acc1, gB, aB);
            fma8(acc2, gC, aC); fma8(acc3, gD, aD);
        }
        for (; j < cnt; ++j) {
            int sA = __shfl(mySrc, j);
            float aA = __shfl(mA, j);
            uint4 gA = *(const uint4*)(h + (size_t)sA * HC2 + c0);
            fma8(acc0, gA, aA);
        }
    }

    float sc = inv[d];
    float4 b0 = *(const float4*)(bias + c0);
    float4 b1 = *(const float4*)(bias + c0 + 4);
    float bb[8] = { b0.x, b0.y, b0.z, b0.w, b1.x, b1.y, b1.z, b1.w };
    u16 os[8];
#pragma unroll
    for (int k = 0; k < 8; ++k) {
        float v = (acc0[k] + acc1[k]) + (acc2[k] + acc3[k]);
        v = v * sc + bb[k];
        v = fmaxf(v, 0.f);                     // relu
        os[k] = f2bf(v);
    }
    uint4 q;
    q.x = (u32)os[0] | ((u32)os[1] << 16);
    q.y = (u32)os[2] | ((u32)os[3] << 16);
    q.z = (u32)os[4] | ((u32)os[5] << 16);
    q.w = (u32)os[6] | ((u32)os[7] << 16);
    *(uint4*)(out + (size_t)d * HC2 + c0) = q;
}

extern "C" void kernel_launch(void* const* d_in, const int* in_sizes, int n_in,
                              void* d_out, int out_size, void* d_ws, size_t ws_size,
                              hipStream_t stream) {
    const float* node      = (const float*)d_in[0];
    const int*   esrc      = (const int*)d_in[1];          // edge_index[0]
    const int*   edst      = ((const int*)d_in[1]) + EE;   // edge_index[1]
    const float* W1        = (const float*)d_in[2];
    const float* att_src1  = (const float*)d_in[3];
    const float* att_dst1  = (const float*)d_in[4];
    const float* b1        = (const float*)d_in[5];
    const float* W2        = (const float*)d_in[6];
    const float* att_src2  = (const float*)d_in[7];
    const float* att_dst2  = (const float*)d_in[8];
    const float* b2        = (const float*)d_in[9];
    const float* fc_w      = (const float*)d_in[10];
    const float* fc_b      = (const float*)d_in[11];
    float* out = (float*)d_out;

    // ---- workspace layout ----
    u16* bufA  = (u16*)d_ws;                        // [NN*HC1]  h1b, later h2b
    u16* bufB  = bufA + (size_t)NN * HC1;           // [NN*HC1]  x2b, later out2b
    u16* nodeb = bufB + (size_t)NN * HC1;           // [NN*F_IN]
    u16* w1t   = nodeb + (size_t)NN * F_IN;         // [HC1*F_IN]
    u16* w2t   = w1t + (size_t)HC1 * F_IN;          // [HC2*HC1]
    u16* fcwt  = w2t + (size_t)HC2 * HC1;           // [OUT_DIM*OUT_DIM]
    float* exal  = (float*)(fcwt + (size_t)OUT_DIM * OUT_DIM);  // [ETOT*H1]
    float* inv   = exal + (size_t)ETOT * H1;        // [NN*H1]
    float* a_s1  = inv + (size_t)NN * H1;           // [NN*H1]
    float* a_d1  = a_s1 + (size_t)NN * H1;
    float* a_s2  = a_d1 + (size_t)NN * H1;          // [NN]
    float* a_d2  = a_s2 + NN;
    int* deg       = (int*)(a_d2 + NN);
    int* cursor    = deg + NN;
    int* row_start = cursor + NN;                   // [NN+1]
    int* slot_src  = row_start + NN + 8;            // [ETOT]

    // ---- conversions ----
    f32_to_bf16_kernel<<<(NN * F_IN + 255) / 256, 256, 0, stream>>>(node, nodeb, NN * F_IN);
    transpose_bf16_kernel<<<dim3(HC1 / 16, F_IN / 16), dim3(16, 16), 0, stream>>>(W1, w1t, F_IN, HC1);
    transpose_bf16_kernel<<<dim3(HC2 / 16, HC1 / 16), dim3(16, 16), 0, stream>>>(W2, w2t, HC1, HC2);
    transpose_bf16_kernel<<<dim3(OUT_DIM / 16, OUT_DIM / 16), dim3(16, 16), 0, stream>>>(fc_w, fcwt, OUT_DIM, OUT_DIM);

    // ---- CSR build ----
    hipMemsetAsync(deg, 0, 2 * NN * sizeof(int), stream);  // deg + cursor
    hist_kernel<<<(ETOT + 255) / 256, 256, 0, stream>>>(edst, deg);
    scan_kernel<<<1, 1024, 0, stream>>>(deg, row_start);
    fill_kernel<<<(ETOT + 255) / 256, 256, 0, stream>>>(esrc, edst, row_start, cursor, slot_src);

    // ---- layer 1 ----
    gemm_bf16<0><<<dim3(HC1 / 128, (NN + 127) / 128), 256, 0, stream>>>(nodeb, w1t, nullptr, bufA, NN, HC1, F_IN);
    att_logits3<H1, C1><<<NN / 2, 128, 0, stream>>>(bufA, att_src1, att_dst1, a_s1, a_d1);
    att_alpha2<H1><<<NN / 2, 128, 0, stream>>>(row_start, slot_src, a_s1, a_d1, exal, inv);
    gat_scatter_l1<<<dim3(NN / 4, HC1 / 256), 128, 0, stream>>>(row_start, slot_src, exal, inv, bufA, b1, bufB);

    // ---- layer 2 ----
    gemm_bf16<0><<<dim3(HC2 / 128, (NN + 127) / 128), 256, 0, stream>>>(bufB, w2t, nullptr, bufA, NN, HC2, HC1);
    att_logits3<H2, C2><<<NN / 2, 128, 0, stream>>>(bufA, att_src2, att_dst2, a_s2, a_d2);
    att_alpha2<H2><<<NN / 2, 128, 0, stream>>>(row_start, slot_src, a_s2, a_d2, exal, inv);
    gat_scatter_l2<<<dim3(NN / 2, HC2 / 512), 128, 0, stream>>>(row_start, slot_src, exal, inv, bufA, b2, bufB);

    // ---- fc: out = relu(out2 @ fc_w + fc_b), f32 out ----
    gemm_bf16<1><<<dim3(OUT_DIM / 128, (NN + 127) / 128), 256, 0, stream>>>(bufB, fcwt, fc_b, out, NN, OUT_DIM, OUT_DIM);
}

// Round 8
// 246.736 us; speedup vs baseline: 1.3603x; 1.0109x over previous
//
#include <hip/hip_runtime.h>
#include <hip/hip_bf16.h>
#include <cstddef>
#include <cstdint>

// Problem constants
#define NN 10000
#define EE 160000
#define ETOT (EE + NN)
#define F_IN 128
#define H1 10
#define C1 128
#define HC1 1280
#define H2 1
#define C2 1024
#define HC2 1024
#define OUT_DIM 1024

typedef __attribute__((ext_vector_type(4))) float f32x4;
typedef __attribute__((ext_vector_type(8))) short s16x8;
typedef unsigned int u32;
typedef unsigned short u16;

__device__ __forceinline__ float bf2f(u16 v) {
    union { u32 u; float f; } x; x.u = ((u32)v) << 16; return x.f;
}
__device__ __forceinline__ float bflo(u32 q) {   // low bf16 of a packed u32
    union { u32 u; float f; } x; x.u = q << 16; return x.f;
}
__device__ __forceinline__ float bfhi(u32 q) {   // high bf16 of a packed u32
    union { u32 u; float f; } x; x.u = q & 0xffff0000u; return x.f;
}
__device__ __forceinline__ u16 f2bf(float f) {
    union { float f; u32 u; } x; x.f = f;
    u32 u = x.u;
    u32 r = (u + 0x7fffu + ((u >> 16) & 1u)) >> 16;   // RNE
    return (u16)r;
}

__device__ __forceinline__ void gld16(const void* g, void* l) {
    __builtin_amdgcn_global_load_lds((const __attribute__((address_space(1))) u32*)g,
                                     (__attribute__((address_space(3))) u32*)l, 16, 0, 0);
}

// Producer-side drain of async global_load_lds BEFORE the barrier (round-6 race fix).
__device__ __forceinline__ void vm_drain() {
    asm volatile("s_waitcnt vmcnt(0)" ::: "memory");
}

// ---------------- conversions ----------------
__global__ void f32_to_bf16_kernel(const float* __restrict__ in, u16* __restrict__ out, int n) {
    int i = blockIdx.x * 256 + threadIdx.x;
    if (i < n) out[i] = f2bf(in[i]);
}

// in: [K][N] row-major f32; out: [N][K] bf16.
__global__ void transpose_bf16_kernel(const float* __restrict__ in, u16* __restrict__ out,
                                      int K, int N) {
    __shared__ u16 t[16][17];
    int n0 = blockIdx.x * 16, k0 = blockIdx.y * 16;
    t[threadIdx.y][threadIdx.x] = f2bf(in[(size_t)(k0 + threadIdx.y) * N + n0 + threadIdx.x]);
    __syncthreads();
    out[(size_t)(n0 + threadIdx.y) * K + k0 + threadIdx.x] = t[threadIdx.x][threadIdx.y];
}

// ---------------- CSR build ----------------
__global__ void hist_kernel(const int* __restrict__ edst, int* __restrict__ deg) {
    int e = blockIdx.x * 256 + threadIdx.x;
    if (e >= ETOT) return;
    int d = (e < EE) ? edst[e] : (e - EE);
    atomicAdd(&deg[d], 1);
}

// shfl-based single-block scan (1024 threads)
__global__ void scan_kernel(const int* __restrict__ deg, int* __restrict__ row_start) {
    __shared__ int wsum[16];
    const int tid = threadIdx.x;
    const int lane = tid & 63;
    const int wid = tid >> 6;
    int carry = 0;
    for (int base = 0; base < NN; base += 1024) {
        int i = base + tid;
        int v = (i < NN) ? deg[i] : 0;
        int x = v;
#pragma unroll
        for (int o = 1; o < 64; o <<= 1) {
            int t = __shfl_up(x, o);
            if (lane >= o) x += t;
        }
        if (lane == 63) wsum[wid] = x;
        __syncthreads();
        if (wid == 0) {
            int w = (lane < 16) ? wsum[lane] : 0;
#pragma unroll
            for (int o = 1; o < 16; o <<= 1) {
                int t = __shfl_up(w, o);
                if (lane >= o) w += t;
            }
            if (lane < 16) wsum[lane] = w;
        }
        __syncthreads();
        int woff = (wid == 0) ? 0 : wsum[wid - 1];
        if (i < NN) row_start[i] = carry + woff + x - v;   // exclusive
        carry += wsum[15];
        __syncthreads();
    }
    if (tid == 0) row_start[NN] = carry;
}

__global__ void fill_kernel(const int* __restrict__ esrc, const int* __restrict__ edst,
                            const int* __restrict__ row_start, int* __restrict__ cursor,
                            int* __restrict__ slot_src) {
    int e = blockIdx.x * 256 + threadIdx.x;
    if (e >= ETOT) return;
    int s, d;
    if (e < EE) { s = esrc[e]; d = edst[e]; }
    else        { s = d = e - EE; }
    int pos = atomicAdd(&cursor[d], 1);
    slot_src[row_start[d] + pos] = s;
}

// ---------------- bf16 MFMA GEMM: C = A[MxK] * Bt[NxK]^T ----------------
// 128x128 tile, 4 waves, 16x16x32 MFMA, BK=32, double-buffered LDS prefetch
// with explicit producer vmcnt drain before each barrier, bijective XCD swizzle.
// BIAS_RELU==1: +bias, relu, f32 out. HEADMAJ==1: store bf16 head-major planes
// [head][M][128] (head = bn/128; requires N multiple of 128, C=128).
template<int BIAS_RELU, int HEADMAJ>
__global__ __launch_bounds__(256, 2)
void gemm_bf16(const u16* __restrict__ A, const u16* __restrict__ Bt,
               const float* __restrict__ bias, void* __restrict__ Cout,
               int M, int N, int K) {
    __shared__ u16 Als[2][128 * 32];
    __shared__ u16 Bls[2][128 * 32];
    const int tid  = threadIdx.x;
    const int wave = tid >> 6;
    const int lane = tid & 63;

    // bijective XCD swizzle
    const int nwg = gridDim.x * gridDim.y;
    const int bid = blockIdx.y * gridDim.x + blockIdx.x;
    const int q = nwg >> 3, r = nwg & 7;
    const int xcd = bid & 7, idx = bid >> 3;
    const int swz = (xcd < r ? xcd * (q + 1) : r * (q + 1) + (xcd - r) * q) + idx;
    const int bm = (swz / gridDim.x) * 128;
    const int bn = (swz % gridDim.x) * 128;

    const int wr = wave >> 1, wc = wave & 1;   // 2x2 waves, each 64x64
    const int lr = lane & 15;
    const int kc = lane >> 4;

    f32x4 acc[4][4] = {};

    const int srow = tid >> 2;
    const int scol = (tid & 3) * 8;
    int arow0 = bm + srow;       if (arow0 >= M) arow0 = M - 1;
    int arow1 = bm + 64 + srow;  if (arow1 >= M) arow1 = M - 1;
    const int brow0 = bn + srow;
    const int brow1 = bn + 64 + srow;

    const u16* aP0 = A  + (size_t)arow0 * K + scol;
    const u16* aP1 = A  + (size_t)arow1 * K + scol;
    const u16* bP0 = Bt + (size_t)brow0 * K + scol;
    const u16* bP1 = Bt + (size_t)brow1 * K + scol;

    // prologue: stage tile 0 into buf 0
    gld16(aP0, &Als[0][(size_t)wave * 512]);
    gld16(aP1, &Als[0][2048 + (size_t)wave * 512]);
    gld16(bP0, &Bls[0][(size_t)wave * 512]);
    gld16(bP1, &Bls[0][2048 + (size_t)wave * 512]);
    vm_drain();
    __syncthreads();

    int cur = 0;
    for (int k0 = 0; k0 < K; k0 += 32) {
        if (k0 + 32 < K) {
            int nxt = cur ^ 1;
            gld16(aP0 + k0 + 32, &Als[nxt][(size_t)wave * 512]);
            gld16(aP1 + k0 + 32, &Als[nxt][2048 + (size_t)wave * 512]);
            gld16(bP0 + k0 + 32, &Bls[nxt][(size_t)wave * 512]);
            gld16(bP1 + k0 + 32, &Bls[nxt][2048 + (size_t)wave * 512]);
        }

        s16x8 af[4], bg[4];
#pragma unroll
        for (int i = 0; i < 4; ++i)
            af[i] = *(const s16x8*)&Als[cur][(wr * 64 + i * 16 + lr) * 32 + kc * 8];
#pragma unroll
        for (int j = 0; j < 4; ++j)
            bg[j] = *(const s16x8*)&Bls[cur][(wc * 64 + j * 16 + lr) * 32 + kc * 8];
#pragma unroll
        for (int i = 0; i < 4; ++i)
#pragma unroll
            for (int j = 0; j < 4; ++j)
                acc[i][j] = __builtin_amdgcn_mfma_f32_16x16x32_bf16(af[i], bg[j], acc[i][j], 0, 0, 0);

        vm_drain();      // prefetch visible to ALL waves before the barrier
        __syncthreads();
        cur ^= 1;
    }

    // C/D layout: col = lane&15, row = (lane>>4)*4 + reg
#pragma unroll
    for (int i = 0; i < 4; ++i) {
#pragma unroll
        for (int r2 = 0; r2 < 4; ++r2) {
            int m = bm + wr * 64 + i * 16 + kc * 4 + r2;
            if (m >= M) continue;
#pragma unroll
            for (int j = 0; j < 4; ++j) {
                int n = bn + wc * 64 + j * 16 + lr;
                float v = acc[i][j][r2];
                if (BIAS_RELU) {
                    v += bias[n];
                    v = fmaxf(v, 0.f);
                    ((float*)Cout)[(size_t)m * N + n] = v;
                } else if (HEADMAJ) {
                    // plane = bn/128, col-in-plane = n - bn
                    ((u16*)Cout)[(size_t)(bn >> 7) * NN * 128 + (size_t)m * 128 + (n - bn)] = f2bf(v);
                } else {
                    ((u16*)Cout)[(size_t)m * N + n] = f2bf(v);
                }
            }
        }
    }
}

// ---------------- logits: 4 ch/lane vector loads ----------------
// PLANAR: h stored as [head][NN][C] planes. H even: half-wave per head pair member.
template<int H, int C, bool PLANAR>
__global__ __launch_bounds__(128)
void att_logits3(const u16* __restrict__ h, const float* __restrict__ att_s,
                 const float* __restrict__ att_d, float* __restrict__ a_s,
                 float* __restrict__ a_d) {
    const int n = blockIdx.x * 2 + (threadIdx.x >> 6);
    const int lane = threadIdx.x & 63;
    if constexpr (H == 1) {
        const u16* row = h + (size_t)n * C;
        float ps = 0.f, pd = 0.f;
        for (int c = lane * 4; c < C; c += 256) {
            uint2 q = *(const uint2*)(row + c);
            float4 s = *(const float4*)(att_s + c);
            float4 dd = *(const float4*)(att_d + c);
            float v0 = bflo(q.x), v1 = bfhi(q.x), v2 = bflo(q.y), v3 = bfhi(q.y);
            ps += v0 * s.x + v1 * s.y + v2 * s.z + v3 * s.w;
            pd += v0 * dd.x + v1 * dd.y + v2 * dd.z + v3 * dd.w;
        }
#pragma unroll
        for (int off = 32; off; off >>= 1) {
            ps += __shfl_down(ps, off);
            pd += __shfl_down(pd, off);
        }
        if (lane == 0) { a_s[n] = ps; a_d[n] = pd; }
    } else {
        const int sub = lane >> 5;        // which head of the pair
        const int lg  = lane & 31;        // 32 lanes x 4ch = 128 = C
#pragma unroll
        for (int hp = 0; hp < H / 2; ++hp) {
            const int hd = hp * 2 + sub;
            const int c = lg * 4;
            const u16* rp = PLANAR ? (h + ((size_t)hd * NN + n) * C + c)
                                   : (h + (size_t)n * H * C + hd * C + c);
            uint2 q = *(const uint2*)rp;
            float4 s = *(const float4*)(att_s + hd * C + c);
            float4 dd = *(const float4*)(att_d + hd * C + c);
            float v0 = bflo(q.x), v1 = bfhi(q.x), v2 = bflo(q.y), v3 = bfhi(q.y);
            float ps = v0 * s.x + v1 * s.y + v2 * s.z + v3 * s.w;
            float pd = v0 * dd.x + v1 * dd.y + v2 * dd.z + v3 * dd.w;
#pragma unroll
            for (int off = 16; off; off >>= 1) {
                ps += __shfl_down(ps, off, 32);
                pd += __shfl_down(pd, off, 32);
            }
            if (lg == 0) {
                a_s[n * H + hd] = ps;
                a_d[n * H + hd] = pd;
            }
        }
    }
}

// ---------------- alpha: unnormalized exp (TRANSPOSED planes [H][ETOT]) + inv sums ----
template<int H>
__global__ __launch_bounds__(128)
void att_alpha3(const int* __restrict__ row_start, const int* __restrict__ slot_src,
                const float* __restrict__ a_s, const float* __restrict__ a_d,
                float* __restrict__ exal_t, float* __restrict__ inv) {
    const int d = blockIdx.x * 2 + (threadIdx.x >> 6);
    const int lane = threadIdx.x & 63;
    const int s0 = row_start[d], s1 = row_start[d + 1];
    float ad[H];
#pragma unroll
    for (int hd = 0; hd < H; ++hd) ad[hd] = a_d[(size_t)d * H + hd];
    float sums[H];
#pragma unroll
    for (int hd = 0; hd < H; ++hd) sums[hd] = 0.f;

    for (int base = s0; base < s1; base += 64) {
        int e = base + lane;
        bool ok = (e < s1);
        int src = ok ? slot_src[e] : 0;
        float as[H];
        if constexpr (H == 1) {
            as[0] = ok ? a_s[src] : 0.f;
        } else {
            const float2* asp = (const float2*)(a_s + (size_t)src * H);
#pragma unroll
            for (int i = 0; i < H / 2; ++i) {
                float2 q = ok ? asp[i] : make_float2(0.f, 0.f);
                as[2 * i] = q.x; as[2 * i + 1] = q.y;
            }
        }
#pragma unroll
        for (int hd = 0; hd < H; ++hd) {
            float t = as[hd] + ad[hd];
            t = (t > 0.f) ? t : 0.2f * t;          // leaky_relu 0.2
            float x = ok ? expf(t) : 0.f;          // logits small by construction
            sums[hd] += x;
            if (ok) exal_t[(size_t)hd * ETOT + e] = x;   // coalesced per plane
        }
    }
#pragma unroll
    for (int hd = 0; hd < H; ++hd) {
#pragma unroll
        for (int off = 32; off; off >>= 1) sums[hd] += __shfl_down(sums[hd], off);
    }
    if (lane == 0) {
#pragma unroll
        for (int hd = 0; hd < H; ++hd) inv[(size_t)d * H + hd] = 1.f / (sums[hd] + 1e-16f);
    }
}

// helper: accumulate 8 channels from a uint4 of packed bf16
__device__ __forceinline__ void fma8(float* acc, uint4 g, float a) {
    acc[0] += a * bflo(g.x); acc[1] += a * bfhi(g.x);
    acc[2] += a * bflo(g.y); acc[3] += a * bfhi(g.y);
    acc[4] += a * bflo(g.z); acc[5] += a * bfhi(g.z);
    acc[6] += a * bflo(g.w); acc[7] += a * bfhi(g.w);
}

// ---------------- scatter v5: L2-resident phases ----------------
// 16-lane groups, 8 ch/lane (16B gathers, 256B contiguous per group per edge).
// PLANAR (layer 1): h = [head][NN][128] planes, blockIdx.y = head -> 2.56 MB
//   working set per phase, L2-resident per XCD.
// !PLANAR (layer 2): h = [NN][HC] node-major, blockIdx.y = 128-ch column slice
//   -> footprint 10000 x 256B = 2.56 MB, also L2-resident.
// ACT: 1 = elu, 2 = relu.
template<int ACT, int H, int HC, bool PLANAR>
__global__ __launch_bounds__(128)
void gat_scatter5(const int* __restrict__ row_start, const int* __restrict__ slot_src,
                  const float* __restrict__ exal_t, const float* __restrict__ inv,
                  const u16* __restrict__ h, const float* __restrict__ bias,
                  u16* __restrict__ out) {
    const int grp = threadIdx.x >> 4;          // 0..7
    const int lg  = threadIdx.x & 15;
    const int d   = blockIdx.x * 8 + grp;
    const int y   = blockIdx.y;                // head (l1) or channel slice (l2)
    const int cc  = y * 128 + lg * 8;          // output channel base
    const int s0 = row_start[d], s1 = row_start[d + 1];
    const float* exp_pl = exal_t + (size_t)(PLANAR ? y : 0) * ETOT;
    const u16* hb = PLANAR ? (h + (size_t)y * NN * 128 + lg * 8)
                           : (h + cc);
    const int hstride = PLANAR ? 128 : HC;

    float acc0[8] = {}, acc1[8] = {}, acc2[8] = {}, acc3[8] = {};

    for (int base = s0; base < s1; base += 16) {
        int e = base + lg;
        bool ok = (e < s1);
        int mySrc = 0; float mA = 0.f;
        if (ok) { mySrc = slot_src[e]; mA = exp_pl[e]; }
        int cnt = min(16, s1 - base);
        int j = 0;
        for (; j + 4 <= cnt; j += 4) {
            int sA = __shfl(mySrc, j, 16),     sB = __shfl(mySrc, j + 1, 16);
            int sC = __shfl(mySrc, j + 2, 16), sD = __shfl(mySrc, j + 3, 16);
            float aA = __shfl(mA, j, 16),     aB = __shfl(mA, j + 1, 16);
            float aC = __shfl(mA, j + 2, 16), aD = __shfl(mA, j + 3, 16);
            uint4 gA = *(const uint4*)(hb + (size_t)sA * hstride);
            uint4 gB = *(const uint4*)(hb + (size_t)sB * hstride);
            uint4 gC = *(const uint4*)(hb + (size_t)sC * hstride);
            uint4 gD = *(const uint4*)(hb + (size_t)sD * hstride);
            fma8(acc0, gA, aA); fma8(acc1, gB, aB);
            fma8(acc2, gC, aC); fma8(acc3, gD, aD);
        }
        for (; j < cnt; ++j) {
            int sA = __shfl(mySrc, j, 16);
            float aA = __shfl(mA, j, 16);
            uint4 gA = *(const uint4*)(hb + (size_t)sA * hstride);
            fma8(acc0, gA, aA);
        }
    }

    float sc = inv[(size_t)d * H + (PLANAR ? y : 0)];
    float4 b0 = *(const float4*)(bias + cc);
    float4 b1 = *(const float4*)(bias + cc + 4);
    float bb[8] = { b0.x, b0.y, b0.z, b0.w, b1.x, b1.y, b1.z, b1.w };
    u16 os[8];
#pragma unroll
    for (int k = 0; k < 8; ++k) {
        float v = (acc0[k] + acc1[k]) + (acc2[k] + acc3[k]);
        v = v * sc + bb[k];
        if (ACT == 1) v = (v > 0.f) ? v : (expf(v) - 1.f);   // elu
        else          v = fmaxf(v, 0.f);                      // relu
        os[k] = f2bf(v);
    }
    uint4 q;
    q.x = (u32)os[0] | ((u32)os[1] << 16);
    q.y = (u32)os[2] | ((u32)os[3] << 16);
    q.z = (u32)os[4] | ((u32)os[5] << 16);
    q.w = (u32)os[6] | ((u32)os[7] << 16);
    *(uint4*)(out + (size_t)d * HC + cc) = q;
}

extern "C" void kernel_launch(void* const* d_in, const int* in_sizes, int n_in,
                              void* d_out, int out_size, void* d_ws, size_t ws_size,
                              hipStream_t stream) {
    const float* node      = (const float*)d_in[0];
    const int*   esrc      = (const int*)d_in[1];          // edge_index[0]
    const int*   edst      = ((const int*)d_in[1]) + EE;   // edge_index[1]
    const float* W1        = (const float*)d_in[2];
    const float* att_src1  = (const float*)d_in[3];
    const float* att_dst1  = (const float*)d_in[4];
    const float* b1        = (const float*)d_in[5];
    const float* W2        = (const float*)d_in[6];
    const float* att_src2  = (const float*)d_in[7];
    const float* att_dst2  = (const float*)d_in[8];
    const float* b2        = (const float*)d_in[9];
    const float* fc_w      = (const float*)d_in[10];
    const float* fc_b      = (const float*)d_in[11];
    float* out = (float*)d_out;

    // ---- workspace layout ----
    u16* bufA  = (u16*)d_ws;                        // [NN*HC1]  h1 planes, later h2
    u16* bufB  = bufA + (size_t)NN * HC1;           // [NN*HC1]  x2b, later out2b
    u16* nodeb = bufB + (size_t)NN * HC1;           // [NN*F_IN]
    u16* w1t   = nodeb + (size_t)NN * F_IN;         // [HC1*F_IN]
    u16* w2t   = w1t + (size_t)HC1 * F_IN;          // [HC2*HC1]
    u16* fcwt  = w2t + (size_t)HC2 * HC1;           // [OUT_DIM*OUT_DIM]
    float* exal  = (float*)(fcwt + (size_t)OUT_DIM * OUT_DIM);  // [H1*ETOT] planes
    float* inv   = exal + (size_t)ETOT * H1;        // [NN*H1]
    float* a_s1  = inv + (size_t)NN * H1;           // [NN*H1]
    float* a_d1  = a_s1 + (size_t)NN * H1;
    float* a_s2  = a_d1 + (size_t)NN * H1;          // [NN]
    float* a_d2  = a_s2 + NN;
    int* deg       = (int*)(a_d2 + NN);
    int* cursor    = deg + NN;
    int* row_start = cursor + NN;                   // [NN+1]
    int* slot_src  = row_start + NN + 8;            // [ETOT]

    // ---- conversions ----
    f32_to_bf16_kernel<<<(NN * F_IN + 255) / 256, 256, 0, stream>>>(node, nodeb, NN * F_IN);
    transpose_bf16_kernel<<<dim3(HC1 / 16, F_IN / 16), dim3(16, 16), 0, stream>>>(W1, w1t, F_IN, HC1);
    transpose_bf16_kernel<<<dim3(HC2 / 16, HC1 / 16), dim3(16, 16), 0, stream>>>(W2, w2t, HC1, HC2);
    transpose_bf16_kernel<<<dim3(OUT_DIM / 16, OUT_DIM / 16), dim3(16, 16), 0, stream>>>(fc_w, fcwt, OUT_DIM, OUT_DIM);

    // ---- CSR build ----
    hipMemsetAsync(deg, 0, 2 * NN * sizeof(int), stream);  // deg + cursor
    hist_kernel<<<(ETOT + 255) / 256, 256, 0, stream>>>(edst, deg);
    scan_kernel<<<1, 1024, 0, stream>>>(deg, row_start);
    fill_kernel<<<(ETOT + 255) / 256, 256, 0, stream>>>(esrc, edst, row_start, cursor, slot_src);

    // ---- layer 1 (h1 stored as head-major planes) ----
    gemm_bf16<0, 1><<<dim3(HC1 / 128, (NN + 127) / 128), 256, 0, stream>>>(nodeb, w1t, nullptr, bufA, NN, HC1, F_IN);
    att_logits3<H1, C1, true><<<NN / 2, 128, 0, stream>>>(bufA, att_src1, att_dst1, a_s1, a_d1);
    att_alpha3<H1><<<NN / 2, 128, 0, stream>>>(row_start, slot_src, a_s1, a_d1, exal, inv);
    gat_scatter5<1, H1, HC1, true><<<dim3(NN / 8, H1), 128, 0, stream>>>(row_start, slot_src, exal, inv, bufA, b1, bufB);

    // ---- layer 2 (node-major, channel-slice phases) ----
    gemm_bf16<0, 0><<<dim3(HC2 / 128, (NN + 127) / 128), 256, 0, stream>>>(bufB, w2t, nullptr, bufA, NN, HC2, HC1);
    att_logits3<H2, C2, false><<<NN / 2, 128, 0, stream>>>(bufA, att_src2, att_dst2, a_s2, a_d2);
    att_alpha3<H2><<<NN / 2, 128, 0, stream>>>(row_start, slot_src, a_s2, a_d2, exal, inv);
    gat_scatter5<2, H2, HC2, false><<<dim3(NN / 8, HC2 / 128), 128, 0, stream>>>(row_start, slot_src, exal, inv, bufA, b2, bufB);

    // ---- fc: out = relu(out2 @ fc_w + fc_b), f32 out ----
    gemm_bf16<1, 0><<<dim3(OUT_DIM / 128, (NN + 127) / 128), 256, 0, stream>>>(bufB, fcwt, fc_b, out, NN, OUT_DIM, OUT_DIM);
}